// Round 8
// baseline (174.806 us; speedup 1.0000x reference)
//
#include <hip/hip_runtime.h>
#include <cstdint>

#define RASTN 256
#define FARV 10.0f
#define FARBITS 0x41200000u   // bits of 10.0f
#define SPLIT 8               // R22: on the fine-interleaved structure, splits
                              // partition entries (no duplicated eval) -> higher
                              // SPLIT divides the heavy center-tiles' per-block
                              // work. R9's "8->150us" was the OLD structure.
#define NBUCK 1024            // counting-sort buckets; width 1/512 (exact dyadic)
#define NINITY 8              // extra prep blocks per batch for zbuf memset

__device__ __forceinline__ float gval(int i) {
    // g = 2*(i+0.5)/256 - 1  -- exact in f32 (multiples of 1/256)
    return (2.0f * ((float)i + 0.5f)) / 256.0f - 1.0f;
}

// ============ Kernel 1: project + prep + counting-sort + inits (grid B x NINITY) =
// R20: sign pre-fold -- if den<0, negate stored edge coeffs + dens (exact in
// IEEE; (-e)/(-d) is bit-identical to e/d), so raster needs no copysign/s0/s1.
__global__ __launch_bounds__(1024) void prep_sort_kernel(
    const float* __restrict__ verts, const int* __restrict__ faces,
    const float* __restrict__ Km, const float* __restrict__ Rm,
    const float* __restrict__ tm, const float* __restrict__ dm,
    float4* __restrict__ rec, uint2* __restrict__ sax, unsigned short* __restrict__ stri,
    unsigned int* __restrict__ zbits, unsigned int* __restrict__ mm,
    float* __restrict__ uvzg, int V, int F, int F2, int B, int npix)
{
#pragma clang fp contract(off)
    __shared__ float s_uvz[1024*3];
    __shared__ unsigned int s_pk[4096];
    __shared__ unsigned short s_bk[4096];
    __shared__ unsigned int s_hist[NBUCK], s_cnt2[NBUCK];
    __shared__ unsigned int s_ws[16];
    int b = blockIdx.x, y = blockIdx.y, tid = threadIdx.x;
    int lane = tid & 63, wv16 = tid >> 6;
    // ---- parallel z-buffer init: each y-block memsets 1/NINITY of this batch ----
    uint4* zb4 = (uint4*)(zbits + (size_t)b * npix);
    int n4 = npix >> 2;
    int sl0 = (n4 * y) / NINITY, sl1 = (n4 * (y + 1)) / NINITY;
    for (int i = sl0 + tid; i < sl1; i += 1024)
        zb4[i] = make_uint4(FARBITS, FARBITS, FARBITS, FARBITS);
    if (y > 0) return;
    if (tid == 0) { mm[2*b] = 0u; mm[2*b+1] = FARBITS; }  // minmax accumulators
    for (int i = tid; i < NBUCK; i += 1024) s_hist[i] = 0u;
    // ---- project (bit-exact replica of reference _project) ----
    bool inlds = (V <= 1024);
    const float* R = Rm + b*9; const float* K = Km + b*9;
    const float* t = tm + b*3; const float* d = dm + b*5;
    for (int v = tid; v < V; v += 1024) {
        float vx = verts[((size_t)b*V + v)*3+0];
        float vy = verts[((size_t)b*V + v)*3+1];
        float vz = verts[((size_t)b*V + v)*3+2];
        float cxm = ((vx*R[0] + vy*R[1]) + vz*R[2]) + t[0];
        float cym = ((vx*R[3] + vy*R[4]) + vz*R[5]) + t[1];
        float czm = ((vx*R[6] + vy*R[7]) + vz*R[8]) + t[2];
        float zd = czm + 1e-9f;
        float x_ = cxm / zd;
        float y_ = cym / zd;
        float k1 = d[0], k2 = d[1], p1 = d[2], p2 = d[3], k3 = d[4];
        float r2   = (x_*x_) + (y_*y_);
        float r2_2 = r2 * r2;
        float r2_3 = r2 * r2_2;
        float radial = ((1.0f + k1*r2) + k2*r2_2) + k3*r2_3;
        float x__ = ((x_*radial) + (((2.0f*p1)*x_)*y_)) + (p2*(r2 + 2.0f*(x_*x_)));
        float y__ = ((y_*radial) + (p1*(r2 + 2.0f*(y_*y_)))) + (((2.0f*p2)*x_)*y_);
        float up = ((x__*K[0]) + (y__*K[1])) + (1.0f*K[2]);
        float vp = ((x__*K[3]) + (y__*K[4])) + (1.0f*K[5]);
        vp = 256.0f - vp;
        float un = (2.0f*(up - 128.0f)) / 256.0f;
        float vn = (2.0f*(vp - 128.0f)) / 256.0f;
        if (inlds) { s_uvz[v*3+0]=un; s_uvz[v*3+1]=vn; s_uvz[v*3+2]=czm; }
        else { uvzg[((size_t)b*V+v)*3+0]=un; uvzg[((size_t)b*V+v)*3+1]=vn; uvzg[((size_t)b*V+v)*3+2]=czm; }
    }
    __syncthreads();
    const float* ub = inlds ? s_uvz : (uvzg + (size_t)b*V*3);
    const int* fb = faces + (size_t)b * F * 3;
    float4* rb = rec + (size_t)b * F2 * 4;
    bool stash = (F2 <= 4096);
    // ---- prep + histogram ----
    for (int j = tid; j < F2; j += 1024) {
        int i0, i1, i2;
        if (j < F) { i0 = fb[j*3+0]; i1 = fb[j*3+1]; i2 = fb[j*3+2]; }
        else { int jj = j - F; i0 = fb[jj*3+2]; i1 = fb[jj*3+1]; i2 = fb[jj*3+0]; }
        float ax = ub[i0*3+0], ay = ub[i0*3+1], az = ub[i0*3+2];
        float bx = ub[i1*3+0], by = ub[i1*3+1], bz = ub[i1*3+2];
        float cx = ub[i2*3+0], cy = ub[i2*3+1], cz = ub[i2*3+2];
        float den = (bx-ax)*(cy-ay) - (by-ay)*(cx-ax);
        bool ok = fabsf(den) > 1e-8f;
        float dens = ok ? den : 1.0f;
        bool alive = ok && (az > 1e-8f) && (bz > 1e-8f) && (cz > 1e-8f);
        float za = (az > 1e-8f) ? az : 1.0f;
        float zb = (bz > 1e-8f) ? bz : 1.0f;
        float zc = (cz > 1e-8f) ? cz : 1.0f;
        float mnx = fminf(ax, fminf(bx, cx));
        float mxx = fmaxf(ax, fmaxf(bx, cx));
        float mny = fminf(ay, fminf(by, cy));
        float mxy = fmaxf(ay, fmaxf(by, cy));
        float m = 1e-3f + 1e-6f*((fabsf(mnx)+fabsf(mxx))+(fabsf(mny)+fabsf(mxy)));
        mnx -= m; mxx += m; mny -= m; mxy += m;
        if (!(mxx >= -1.0f) || !(mnx <= 1.0f) || !(mxy >= -1.0f) || !(mny <= 1.0f)) alive = false;
        int ic0 = 1, ic1 = 0, ir0 = 1, ir1 = 0;
        float minz = 3e38f;
        if (alive) {
            float lx = fmaxf(mnx, -1.5f), hx = fminf(mxx, 1.5f);
            float ly = fmaxf(mny, -1.5f), hy = fminf(mxy, 1.5f);
            ic0 = (int)floorf((lx + 1.0f) * 128.0f - 0.5f);
            ic1 = (int)ceilf ((hx + 1.0f) * 128.0f - 0.5f);
            ir0 = (int)floorf((ly + 1.0f) * 128.0f - 0.5f);
            ir1 = (int)ceilf ((hy + 1.0f) * 128.0f - 0.5f);
            ic0 = ic0 < 0 ? 0 : ic0;  ir0 = ir0 < 0 ? 0 : ir0;
            ic1 = ic1 > 255 ? 255 : ic1;  ir1 = ir1 > 255 ? 255 : ir1;
            if (ic0 > ic1 || ir0 > ir1) { ic0 = 1; ic1 = 0; ir0 = 1; ir1 = 0; minz = 3e38f; }
            else minz = fminf(za, fminf(zb, zc)) * (1.0f - 4e-4f);  // conservative early-z key
        }
        float minzv = fminf(za, fminf(zb, zc));
        float maxzv = fmaxf(za, fmaxf(zb, zc));
        // ---- sign pre-fold: stored dens >= 0, edge coeffs negated to match.
        // (-e)/(-d) is bit-identical to e/d in IEEE -> exact path unchanged.
        float a0 = by - cy, b0 = cx - bx;
        float a1 = cy - ay, b1 = ax - cx;
        float densf = dens;
        if (dens < 0.0f) { a0 = -a0; b0 = -b0; a1 = -a1; b1 = -b1; densf = -dens; }
        float rd = __builtin_amdgcn_rcpf(densf);
        float ra, rbz, rc;
        if (minzv > 1e-2f && maxzv < 100.0f * minzv) {
            ra  = __builtin_amdgcn_rcpf(za);
            rbz = __builtin_amdgcn_rcpf(zb);
            rc  = __builtin_amdgcn_rcpf(zc);
        } else {
            ra = rbz = rc = __builtin_huge_valf();   // filters disabled -> exact path
        }
        unsigned int pack = (unsigned int)(ic0 | (ic1 << 8) | (ir0 << 16) | (ir1 << 24));
        int bk = NBUCK - 1;                          // dead -> last bucket (huge key)
        if (minz < 1e30f) {
            bk = (int)(minz * 512.0f);               // floor; bucket LB = bk/512 exact
            bk = bk < 0 ? 0 : (bk > NBUCK-2 ? NBUCK-2 : bk);
        }
        size_t base = (size_t)j * 4;
        rb[base+0] = make_float4(cx, cy, a0, b0);
        rb[base+1] = make_float4(a1, b1, rd, ra);
        rb[base+2] = make_float4(densf, za, zb, zc);
        rb[base+3] = make_float4(__uint_as_float(pack), minz, rbz, rc);
        atomicAdd(&s_hist[bk], 1u);
        if (stash) { s_pk[j] = pack; s_bk[j] = (unsigned short)bk; }
    }
    __syncthreads();
    // ---- exclusive prefix over NBUCK buckets: shfl wave-scan, 3 barriers --------
    {
        unsigned int h = s_hist[tid];        // NBUCK == blockDim == 1024
        unsigned int v = h;
        for (int o = 1; o < 64; o <<= 1) {
            unsigned int tsh = __shfl_up(v, o, 64);
            if (lane >= o) v += tsh;
        }
        if (lane == 63) s_ws[wv16] = v;      // 16 wave totals
        __syncthreads();
        if (tid < 16) {
            unsigned int w = s_ws[tid];
            for (int o = 1; o < 16; o <<= 1) {
                unsigned int tsh = __shfl_up(w, o, 64);
                if (tid >= o) w += tsh;
            }
            s_ws[tid] = w;                   // inclusive wave-total scan
        }
        __syncthreads();
        unsigned int add = (wv16 > 0) ? s_ws[wv16 - 1] : 0u;
        s_cnt2[tid] = v + add - h;           // exclusive offsets
    }
    __syncthreads();
    // ---- scatter (order within bucket arbitrary; key = bucket LB -> conservative) --
    uint2* sxb = sax + (size_t)b * F2;
    unsigned short* stb = stri + (size_t)b * F2;
    for (int j = tid; j < F2; j += 1024) {
        unsigned int pack; int bk;
        if (stash) { pack = s_pk[j]; bk = (int)s_bk[j]; }
        else {
            float4 q3 = rb[(size_t)j*4+3];
            pack = __float_as_uint(q3.x);
            float mz = q3.y;
            bk = NBUCK - 1;
            if (mz < 1e30f) { bk = (int)(mz * 512.0f); bk = bk < 0 ? 0 : (bk > NBUCK-2 ? NBUCK-2 : bk); }
        }
        float key = (bk == NBUCK-1) ? 3e38f : (float)bk * (1.0f/512.0f);  // exact dyadic LB
        int pos = (int)atomicAdd(&s_cnt2[bk], 1u);
        sxb[pos] = make_uint2(pack, __float_as_uint(key));
        stb[pos] = (unsigned short)j;
    }
}

// ============ Kernel 2: tile raster, SPLIT blocks/tile, shared per-pixel z =======
// R22 = R21 body, SPLIT 4 -> 8. Three flat micro-opt rounds (R19-R21) falsified
// issue-bound and per-iteration-latency models; remaining hypothesis is tail
// imbalance (center tiles own most listed entries). Fine-grained rank interleave
// means splits PARTITION entries -> SPLIT=8 halves the heavy blocks' work with
// only fixed per-block overhead added. (R9's SPLIT=8=150us was pre-interleave.)
__global__ __launch_bounds__(256) void raster_kernel(
    const float4* __restrict__ rec, const uint2* __restrict__ sax,
    const unsigned short* __restrict__ stri, unsigned int* __restrict__ zbits,
    int F2)
{
#pragma clang fp contract(off)
    __shared__ float4 sh[256];                 // 64 tris x 4 records
    __shared__ float2 s_kb[256];               // (sort key, bbox-pack-as-float)
    __shared__ unsigned short s_list[256];
    __shared__ int s_wk[4], s_kk[4], s_wo[4];
    __shared__ int s_tot, s_kc;
    __shared__ float s_tzmax, s_red[4];
    int zz = blockIdx.z;
    int b = zz / SPLIT, sp = zz - b*SPLIT;
    int tc = blockIdx.x, tr = blockIdx.y;
    int tid = threadIdx.x, lane = tid & 63, wv = tid >> 6;
    int tx = tid & 15, ty = tid >> 4;
    int col = tc*16 + tx, row = tr*16 + ty;
    float X = gval(col), Y = gval(row);
    int pc0 = tc*16, pc1 = pc0+15, pr0 = tr*16, pr1 = pr0+15;
    int wvs = __builtin_amdgcn_readfirstlane(wv);   // wave-uniform -> SGPR
    int wr0 = pr0 + wvs*4, wr1 = wr0 + 3;           // this wave's 4-row strip
    // tile rect over pixel CENTERS, for bin-time edge culling
    float Xc = 0.5f*(gval(pc0) + gval(pc1));
    float Yc = 0.5f*(gval(pr0) + gval(pr1));
    const float hxr = 15.0f/256.0f, hyr = 15.0f/256.0f;
    const float4* rb = rec + (size_t)b * F2 * 4;
    const uint2* sxb = sax + (size_t)b * F2;
    const unsigned short* stb = stri + (size_t)b * F2;
    size_t pix = ((size_t)b*RASTN + row)*RASTN + col;
    unsigned int* zp_g = zbits + pix;
    float zmin = FARV;
    float pushed = FARV;     // min value known to already be in zbits[pix]
    if (tid == 0) s_tzmax = FARV;
    __syncthreads();
    int nch = (F2 + 256*SPLIT - 1) / (256*SPLIT);
    for (int c = 0; c < nch; ++c) {
        // rank interleaved at fine granularity: all splits converge on the front
        int s = (c*256 + tid)*SPLIT + sp;
        bool kp = false, sv = false; unsigned int tri = 0; float kf = 0.0f;
        unsigned int pkv = 0;
        if (s < F2) {
            uint2 a = sxb[s];
            kf = __uint_as_float(a.y);
            kp = !(kf > s_tzmax);                  // conservative early-z (key <= minz)
            if (kp) {
                int pk = (int)a.x;
                int ic0 = pk & 255, ic1 = (pk >> 8) & 255;
                int ir0 = (pk >> 16) & 255, ir1 = (pk >> 24) & 255;
                sv = (ic0 <= ic1) && (ic0 <= pc1) && (ic1 >= pc0) && (ir0 <= pr1) && (ir1 >= pr0);
                if (sv) {
                    tri = stb[s];
                    pkv = a.x;
                    // ---- conservative 3-edge rect cull (per-thread, parallel;
                    //      folded coeffs -> no sign factor) ----
                    float4 q0 = rb[(size_t)tri*4 + 0];
                    float4 q1 = rb[(size_t)tri*4 + 1];
                    float4 q2 = rb[(size_t)tri*4 + 2];
                    float a0 = q0.z, b0 = q0.w;
                    float a1 = q1.x, b1 = q1.y;
                    float xcd = Xc - q0.x, ycd = Yc - q0.y;
                    float e0c = (a0*xcd) + (b0*ycd);
                    float e1c = (a1*xcd) + (b1*ycd);
                    float den = q2.x;                  // folded: >= 0
                    float e2c = (den - e0c) - e1c;
                    float a2 = -(a0 + a1), b2 = -(b0 + b1);
                    float t0 = fabsf(a0)*hxr + fabsf(b0)*hyr;
                    float t1 = fabsf(a1)*hxr + fabsf(b1)*hyr;
                    float t2 = fabsf(a2)*hxr + fabsf(b2)*hyr;
                    float m0 = e0c + t0;
                    float m1 = e1c + t1;
                    float m2 = e2c + t2;
                    // relative margins swamp f32 eval error; cull only if provably
                    // every pixel center has a strictly negative barycentric
                    bool cull = (m0 < -1e-5f*(fabsf(e0c) + t0 + 1.0f))
                             || (m1 < -1e-5f*(fabsf(e1c) + t1 + 1.0f))
                             || (m2 < -1e-5f*(fabsf(e2c) + t2 + 1.0f));
                    if (cull) sv = false;
                }
            }
        }
        unsigned long long bs = __ballot(sv ? 1 : 0);
        unsigned long long bk = __ballot(kp ? 1 : 0);
        int pfx = __popcll(bs & ((1ull << lane) - 1ull));
        if (lane == 0) { s_wk[wv] = __popcll(bs); s_kk[wv] = __popcll(bk); }
        __syncthreads();
        if (tid == 0) {
            int acc = 0;
            for (int q = 0; q < 4; ++q) { s_wo[q] = acc; acc += s_wk[q]; }
            s_tot = acc;
            s_kc = s_kk[0] + s_kk[1] + s_kk[2] + s_kk[3];
        }
        __syncthreads();
        if (sv) {
            int pos = s_wo[wv] + pfx;
            s_list[pos] = (unsigned short)tri;
            s_kb[pos] = make_float2(kf, __uint_as_float(pkv));  // monotone keys
        }
        int kcnt = s_kc, n = s_tot;
        if (kcnt == 0) break;   // keys non-decreasing: all remaining > tzmax
        for (int g = 0; g < n; g += 64) {
            __syncthreads();
            // issue shared-z pull + per-lane (key,bbox) copy FIRST: the staging
            // barrier's implicit waits absorb their latency.
            float zg = __uint_as_float(__hip_atomic_load(
                zp_g, __ATOMIC_RELAXED, __HIP_MEMORY_SCOPE_AGENT));
            float2 kbv = s_kb[g + lane];   // lane l holds pair g+l (2-way, free)
            int cnt2 = (n - g) < 64 ? (n - g) : 64;
            if (tid < cnt2*4) {
                unsigned int t4 = s_list[g + (tid >> 2)];
                sh[tid] = rb[(size_t)t4*4 + (tid & 3)];
            }
            __syncthreads();
            pushed = fminf(pushed, zg);
            zmin = fminf(zmin, zg);
            int vkey = __float_as_int(kbv.x);
            int vbb  = __float_as_int(kbv.y);
            for (int i = 0; i < cnt2; ++i) {
                // register-file loop head: readlane (~4cy) replaces ds_read_b64
                float ky = __int_as_float(__builtin_amdgcn_readlane(vkey, i));
                if (ky > zmin) break;          // monotone: lane permanently done
                unsigned int pk = (unsigned int)__builtin_amdgcn_readlane(vbb, i);
                int ir0 = (int)((pk >> 16) & 255u), ir1 = (int)(pk >> 24);
                if (ir1 < wr0 || ir0 > wr1) continue;   // scalar row-strip reject
                int ic0 = (int)(pk & 255u), ic1 = (int)((pk >> 8) & 255u);
                if (col < ic0 || col > ic1 || row < ir0 || row > ir1) continue;
                float4 q0 = sh[i*4+0];
                float4 q1 = sh[i*4+1];
                float xc = X - q0.x;
                float yc = Y - q0.y;
                float e0 = (q0.z*xc) + (q0.w*yc);  // folded w0 numerator (= s0)
                float e1 = (q1.x*xc) + (q1.y*yc);  // folded w1 numerator
                float rd = q1.z;                   // rcp(dens), dens >= 0
                float w0a = e0*rd, w1a = e1*rd;    // approx w (filter only)
                float w2a = (1.0f - w0a) - w1a;
                float epsu = 1e-4f*((1.0f + fabsf(w0a)) + fabsf(w1a));
                if (e0 > -1e-30f && e1 > -1e-30f && w2a > -epsu) {
                    float4 q3 = sh[i*4+3];         // rcp(zb), rcp(zc) for candidates only
                    float inva = ((w0a*q1.w) + (w1a*q3.z)) + (w2a*q3.w);
                    float zpa = __builtin_amdgcn_rcpf(inva);
                    bool clearly = (e0 > 0.0f) && (e1 > 0.0f) && (w2a > epsu) && (inva > 1e-6f);
                    // clearly-valid + approx-zp above zmin (w/ margin) provably
                    // cannot change the exact min -> skip the 6 IEEE divides
                    if (!clearly || zpa < zmin*1.001f) {
                        float4 q2 = sh[i*4+2];
                        float dens = q2.x;
                        float w0 = e0 / dens;      // (-e)/(-d) bit-exact == ref
                        float w1 = e1 / dens;
                        float w2 = (1.0f - w0) - w1;
                        float inv = ((w0 / q2.y) + (w1 / q2.z)) + (w2 / q2.w);
                        if ((w0 >= 0.0f) && (w1 >= 0.0f) && (w2 >= 0.0f) && (inv > 1e-8f)) {
                            float zp = 1.0f / inv; // exact div == ref zp
                            zmin = fminf(zmin, zp);
                        }
                    }
                }
            }
            // ---- push improvement so other splits can skip their warm-up
            if (zmin < pushed) {
                atomicMin(zp_g, __float_as_uint(zmin));   // bit-monotone positive floats
                pushed = zmin;
            }
        }
        if (n > 0) {
            // tile zmax refresh: only shrinks -> stays a conservative upper bound
            float zx = zmin;
            for (int o = 32; o; o >>= 1) zx = fmaxf(zx, __shfl_xor(zx, o));
            if (lane == 0) s_red[wv] = zx;
        }
        __syncthreads();
        if (n > 0 && tid == 0)
            s_tzmax = fminf(s_tzmax,
                fmaxf(fmaxf(s_red[0], s_red[1]), fmaxf(s_red[2], s_red[3])));
        __syncthreads();
    }
    if (zmin < pushed)
        atomicMin(zp_g, __float_as_uint(zmin));   // final publish
}

// ============ Kernel 3: per-batch minmax reduction + mask write (float4) =========
__global__ __launch_bounds__(256) void minmax_kernel(
    const float4* __restrict__ zbuf, float4* __restrict__ mask,
    unsigned int* __restrict__ mm, int npix)
{
    __shared__ float smx[4], smn[4];
    int b = blockIdx.y;
    size_t i4 = (((size_t)b * npix) >> 2) + (size_t)blockIdx.x * 256 + threadIdx.x;
    float4 z = zbuf[i4];
    float4 mk;
    mk.x = (z.x < FARV) ? 1.0f : 0.0f;
    mk.y = (z.y < FARV) ? 1.0f : 0.0f;
    mk.z = (z.z < FARV) ? 1.0f : 0.0f;
    mk.w = (z.w < FARV) ? 1.0f : 0.0f;
    mask[i4] = mk;                            // cover == any valid hit (z < FAR)
    float nbx = (z.x == FARV) ? 0.0f : z.x;   // (1-img_inf)*img
    float nby = (z.y == FARV) ? 0.0f : z.y;
    float nbz = (z.z == FARV) ? 0.0f : z.z;
    float nbw = (z.w == FARV) ? 0.0f : z.w;
    float vmx = fmaxf(fmaxf(nbx, nby), fmaxf(nbz, nbw));
    float vmn = fminf(fminf(z.x, z.y), fminf(z.z, z.w));
    int lane = threadIdx.x & 63, wv = threadIdx.x >> 6;
    for (int o = 32; o; o >>= 1) {
        vmx = fmaxf(vmx, __shfl_xor(vmx, o));
        vmn = fminf(vmn, __shfl_xor(vmn, o));
    }
    if (lane == 0) { smx[wv] = vmx; smn[wv] = vmn; }
    __syncthreads();
    if (threadIdx.x == 0) {
        float bmx = fmaxf(fmaxf(smx[0], smx[1]), fmaxf(smx[2], smx[3]));
        float bmn = fminf(fminf(smn[0], smn[1]), fminf(smn[2], smn[3]));
        atomicMax(mm + 2*b,     __float_as_uint(bmx));   // positive floats: bit-monotone
        atomicMin(mm + 2*b + 1, __float_as_uint(bmn));
    }
}

// ============ Kernel 4: normalize depth in place (float4) ========================
__global__ __launch_bounds__(256) void final_kernel(
    float4* __restrict__ zdep, const unsigned int* __restrict__ mm,
    int npix4, int total4)
{
#pragma clang fp contract(off)
    int idx = blockIdx.x*256 + threadIdx.x;
    if (idx >= total4) return;
    int b = idx / npix4;
    float mx = __uint_as_float(mm[2*b]);
    float mn = __uint_as_float(mm[2*b + 1]);
    float den = (mx - mn) + 1e-4f;
    float4 z = zdep[idx];
    float4 r;
    r.x = (mx - z.x) / den;
    r.y = (mx - z.y) / den;
    r.z = (mx - z.z) / den;
    r.w = (mx - z.w) / den;
    r.x = r.x < 0.0f ? 0.0f : (r.x > 1.0f ? 1.0f : r.x);
    r.y = r.y < 0.0f ? 0.0f : (r.y > 1.0f ? 1.0f : r.y);
    r.z = r.z < 0.0f ? 0.0f : (r.z > 1.0f ? 1.0f : r.z);
    r.w = r.w < 0.0f ? 0.0f : (r.w > 1.0f ? 1.0f : r.w);
    zdep[idx] = r;
}

extern "C" void kernel_launch(void* const* d_in, const int* in_sizes, int n_in,
                              void* d_out, int out_size, void* d_ws, size_t ws_size,
                              hipStream_t stream)
{
    const float* verts = (const float*)d_in[0];
    const int*   faces = (const int*)d_in[1];
    const float* Km    = (const float*)d_in[2];
    const float* Rm    = (const float*)d_in[3];
    const float* tm    = (const float*)d_in[4];
    const float* dm    = (const float*)d_in[5];
    float* out = (float*)d_out;

    int B  = in_sizes[2] / 9;          // intr is B*3*3
    int V  = in_sizes[0] / (3 * B);
    int F  = in_sizes[1] / (3 * B);
    int F2 = 2 * F;
    int npix = RASTN * RASTN;

    char* ws = (char*)d_ws;
    size_t off = 0;
    float4* rec = (float4*)(ws + off);
    off = (off + (size_t)B * F2 * 4 * sizeof(float4) + 255) & ~(size_t)255;
    uint2* sax = (uint2*)(ws + off);
    off = (off + (size_t)B * F2 * sizeof(uint2) + 255) & ~(size_t)255;
    unsigned short* stri = (unsigned short*)(ws + off);
    off = (off + (size_t)B * F2 * sizeof(unsigned short) + 255) & ~(size_t)255;
    float* uvzg = (float*)(ws + off);
    off = (off + (size_t)B * V * 3 * sizeof(float) + 255) & ~(size_t)255;
    unsigned int* mm = (unsigned int*)(ws + off);

    unsigned int* zbits = (unsigned int*)out;    // depth region doubles as zbuf
    float* mask = out + (size_t)B * npix;

    dim3 pgrid(B, NINITY);
    prep_sort_kernel<<<pgrid, 1024, 0, stream>>>(
        verts, faces, Km, Rm, tm, dm, rec, sax, stri, zbits, mm, uvzg,
        V, F, F2, B, npix);
    dim3 rgrid(16, 16, B * SPLIT);
    raster_kernel<<<rgrid, 256, 0, stream>>>(rec, sax, stri, zbits, F2);
    dim3 mgrid(npix / 1024, B);
    minmax_kernel<<<mgrid, 256, 0, stream>>>(
        (const float4*)zbits, (float4*)mask, mm, npix);
    int npix4 = npix >> 2;
    int total4 = B * npix4;
    final_kernel<<<(total4 + 255) / 256, 256, 0, stream>>>(
        (float4*)zbits, mm, npix4, total4);
}

// Round 9
// 173.028 us; speedup vs baseline: 1.0103x; 1.0103x over previous
//
#include <hip/hip_runtime.h>
#include <cstdint>

#define RASTN 256
#define FARV 10.0f
#define FARBITS 0x41200000u   // bits of 10.0f
#define SPLIT 4               // R22: 8 regressed (dup z-traffic); 4 is optimum
#define NBUCK 1024            // counting-sort buckets; width 1/512 (exact dyadic)
#define NINITY 8              // extra prep blocks per batch for zbuf memset

__device__ __forceinline__ float gval(int i) {
    // g = 2*(i+0.5)/256 - 1  -- exact in f32 (multiples of 1/256)
    return (2.0f * ((float)i + 0.5f)) / 256.0f - 1.0f;
}

__device__ __forceinline__ float rl(float v, int i) {
    // readlane: register-file broadcast of lane i's value (exec-independent)
    return __int_as_float(__builtin_amdgcn_readlane(__float_as_int(v), i));
}

// ============ Kernel 1: project + prep + counting-sort + inits (grid B x NINITY) =
// R20: sign pre-fold -- if den<0, negate stored edge coeffs + dens (exact in
// IEEE; (-e)/(-d) is bit-identical to e/d), so raster needs no copysign/s0/s1.
__global__ __launch_bounds__(1024) void prep_sort_kernel(
    const float* __restrict__ verts, const int* __restrict__ faces,
    const float* __restrict__ Km, const float* __restrict__ Rm,
    const float* __restrict__ tm, const float* __restrict__ dm,
    float4* __restrict__ rec, uint2* __restrict__ sax, unsigned short* __restrict__ stri,
    unsigned int* __restrict__ zbits, unsigned int* __restrict__ mm,
    float* __restrict__ uvzg, int V, int F, int F2, int B, int npix)
{
#pragma clang fp contract(off)
    __shared__ float s_uvz[1024*3];
    __shared__ unsigned int s_pk[4096];
    __shared__ unsigned short s_bk[4096];
    __shared__ unsigned int s_hist[NBUCK], s_cnt2[NBUCK];
    __shared__ unsigned int s_ws[16];
    int b = blockIdx.x, y = blockIdx.y, tid = threadIdx.x;
    int lane = tid & 63, wv16 = tid >> 6;
    // ---- parallel z-buffer init: each y-block memsets 1/NINITY of this batch ----
    uint4* zb4 = (uint4*)(zbits + (size_t)b * npix);
    int n4 = npix >> 2;
    int sl0 = (n4 * y) / NINITY, sl1 = (n4 * (y + 1)) / NINITY;
    for (int i = sl0 + tid; i < sl1; i += 1024)
        zb4[i] = make_uint4(FARBITS, FARBITS, FARBITS, FARBITS);
    if (y > 0) return;
    if (tid == 0) { mm[2*b] = 0u; mm[2*b+1] = FARBITS; }  // minmax accumulators
    for (int i = tid; i < NBUCK; i += 1024) s_hist[i] = 0u;
    // ---- project (bit-exact replica of reference _project) ----
    bool inlds = (V <= 1024);
    const float* R = Rm + b*9; const float* K = Km + b*9;
    const float* t = tm + b*3; const float* d = dm + b*5;
    for (int v = tid; v < V; v += 1024) {
        float vx = verts[((size_t)b*V + v)*3+0];
        float vy = verts[((size_t)b*V + v)*3+1];
        float vz = verts[((size_t)b*V + v)*3+2];
        float cxm = ((vx*R[0] + vy*R[1]) + vz*R[2]) + t[0];
        float cym = ((vx*R[3] + vy*R[4]) + vz*R[5]) + t[1];
        float czm = ((vx*R[6] + vy*R[7]) + vz*R[8]) + t[2];
        float zd = czm + 1e-9f;
        float x_ = cxm / zd;
        float y_ = cym / zd;
        float k1 = d[0], k2 = d[1], p1 = d[2], p2 = d[3], k3 = d[4];
        float r2   = (x_*x_) + (y_*y_);
        float r2_2 = r2 * r2;
        float r2_3 = r2 * r2_2;
        float radial = ((1.0f + k1*r2) + k2*r2_2) + k3*r2_3;
        float x__ = ((x_*radial) + (((2.0f*p1)*x_)*y_)) + (p2*(r2 + 2.0f*(x_*x_)));
        float y__ = ((y_*radial) + (p1*(r2 + 2.0f*(y_*y_)))) + (((2.0f*p2)*x_)*y_);
        float up = ((x__*K[0]) + (y__*K[1])) + (1.0f*K[2]);
        float vp = ((x__*K[3]) + (y__*K[4])) + (1.0f*K[5]);
        vp = 256.0f - vp;
        float un = (2.0f*(up - 128.0f)) / 256.0f;
        float vn = (2.0f*(vp - 128.0f)) / 256.0f;
        if (inlds) { s_uvz[v*3+0]=un; s_uvz[v*3+1]=vn; s_uvz[v*3+2]=czm; }
        else { uvzg[((size_t)b*V+v)*3+0]=un; uvzg[((size_t)b*V+v)*3+1]=vn; uvzg[((size_t)b*V+v)*3+2]=czm; }
    }
    __syncthreads();
    const float* ub = inlds ? s_uvz : (uvzg + (size_t)b*V*3);
    const int* fb = faces + (size_t)b * F * 3;
    float4* rb = rec + (size_t)b * F2 * 4;
    bool stash = (F2 <= 4096);
    // ---- prep + histogram ----
    for (int j = tid; j < F2; j += 1024) {
        int i0, i1, i2;
        if (j < F) { i0 = fb[j*3+0]; i1 = fb[j*3+1]; i2 = fb[j*3+2]; }
        else { int jj = j - F; i0 = fb[jj*3+2]; i1 = fb[jj*3+1]; i2 = fb[jj*3+0]; }
        float ax = ub[i0*3+0], ay = ub[i0*3+1], az = ub[i0*3+2];
        float bx = ub[i1*3+0], by = ub[i1*3+1], bz = ub[i1*3+2];
        float cx = ub[i2*3+0], cy = ub[i2*3+1], cz = ub[i2*3+2];
        float den = (bx-ax)*(cy-ay) - (by-ay)*(cx-ax);
        bool ok = fabsf(den) > 1e-8f;
        float dens = ok ? den : 1.0f;
        bool alive = ok && (az > 1e-8f) && (bz > 1e-8f) && (cz > 1e-8f);
        float za = (az > 1e-8f) ? az : 1.0f;
        float zb = (bz > 1e-8f) ? bz : 1.0f;
        float zc = (cz > 1e-8f) ? cz : 1.0f;
        float mnx = fminf(ax, fminf(bx, cx));
        float mxx = fmaxf(ax, fmaxf(bx, cx));
        float mny = fminf(ay, fminf(by, cy));
        float mxy = fmaxf(ay, fmaxf(by, cy));
        float m = 1e-3f + 1e-6f*((fabsf(mnx)+fabsf(mxx))+(fabsf(mny)+fabsf(mxy)));
        mnx -= m; mxx += m; mny -= m; mxy += m;
        if (!(mxx >= -1.0f) || !(mnx <= 1.0f) || !(mxy >= -1.0f) || !(mny <= 1.0f)) alive = false;
        int ic0 = 1, ic1 = 0, ir0 = 1, ir1 = 0;
        float minz = 3e38f;
        if (alive) {
            float lx = fmaxf(mnx, -1.5f), hx = fminf(mxx, 1.5f);
            float ly = fmaxf(mny, -1.5f), hy = fminf(mxy, 1.5f);
            ic0 = (int)floorf((lx + 1.0f) * 128.0f - 0.5f);
            ic1 = (int)ceilf ((hx + 1.0f) * 128.0f - 0.5f);
            ir0 = (int)floorf((ly + 1.0f) * 128.0f - 0.5f);
            ir1 = (int)ceilf ((hy + 1.0f) * 128.0f - 0.5f);
            ic0 = ic0 < 0 ? 0 : ic0;  ir0 = ir0 < 0 ? 0 : ir0;
            ic1 = ic1 > 255 ? 255 : ic1;  ir1 = ir1 > 255 ? 255 : ir1;
            if (ic0 > ic1 || ir0 > ir1) { ic0 = 1; ic1 = 0; ir0 = 1; ir1 = 0; minz = 3e38f; }
            else minz = fminf(za, fminf(zb, zc)) * (1.0f - 4e-4f);  // conservative early-z key
        }
        float minzv = fminf(za, fminf(zb, zc));
        float maxzv = fmaxf(za, fmaxf(zb, zc));
        // ---- sign pre-fold: stored dens >= 0, edge coeffs negated to match.
        // (-e)/(-d) is bit-identical to e/d in IEEE -> exact path unchanged.
        float a0 = by - cy, b0 = cx - bx;
        float a1 = cy - ay, b1 = ax - cx;
        float densf = dens;
        if (dens < 0.0f) { a0 = -a0; b0 = -b0; a1 = -a1; b1 = -b1; densf = -dens; }
        float rd = __builtin_amdgcn_rcpf(densf);
        float ra, rbz, rc;
        if (minzv > 1e-2f && maxzv < 100.0f * minzv) {
            ra  = __builtin_amdgcn_rcpf(za);
            rbz = __builtin_amdgcn_rcpf(zb);
            rc  = __builtin_amdgcn_rcpf(zc);
        } else {
            ra = rbz = rc = __builtin_huge_valf();   // filters disabled -> exact path
        }
        unsigned int pack = (unsigned int)(ic0 | (ic1 << 8) | (ir0 << 16) | (ir1 << 24));
        int bk = NBUCK - 1;                          // dead -> last bucket (huge key)
        if (minz < 1e30f) {
            bk = (int)(minz * 512.0f);               // floor; bucket LB = bk/512 exact
            bk = bk < 0 ? 0 : (bk > NBUCK-2 ? NBUCK-2 : bk);
        }
        size_t base = (size_t)j * 4;
        rb[base+0] = make_float4(cx, cy, a0, b0);
        rb[base+1] = make_float4(a1, b1, rd, ra);
        rb[base+2] = make_float4(densf, za, zb, zc);
        rb[base+3] = make_float4(__uint_as_float(pack), minz, rbz, rc);
        atomicAdd(&s_hist[bk], 1u);
        if (stash) { s_pk[j] = pack; s_bk[j] = (unsigned short)bk; }
    }
    __syncthreads();
    // ---- exclusive prefix over NBUCK buckets: shfl wave-scan, 3 barriers --------
    {
        unsigned int h = s_hist[tid];        // NBUCK == blockDim == 1024
        unsigned int v = h;
        for (int o = 1; o < 64; o <<= 1) {
            unsigned int tsh = __shfl_up(v, o, 64);
            if (lane >= o) v += tsh;
        }
        if (lane == 63) s_ws[wv16] = v;      // 16 wave totals
        __syncthreads();
        if (tid < 16) {
            unsigned int w = s_ws[tid];
            for (int o = 1; o < 16; o <<= 1) {
                unsigned int tsh = __shfl_up(w, o, 64);
                if (tid >= o) w += tsh;
            }
            s_ws[tid] = w;                   // inclusive wave-total scan
        }
        __syncthreads();
        unsigned int add = (wv16 > 0) ? s_ws[wv16 - 1] : 0u;
        s_cnt2[tid] = v + add - h;           // exclusive offsets
    }
    __syncthreads();
    // ---- scatter (order within bucket arbitrary; key = bucket LB -> conservative) --
    uint2* sxb = sax + (size_t)b * F2;
    unsigned short* stb = stri + (size_t)b * F2;
    for (int j = tid; j < F2; j += 1024) {
        unsigned int pack; int bk;
        if (stash) { pack = s_pk[j]; bk = (int)s_bk[j]; }
        else {
            float4 q3 = rb[(size_t)j*4+3];
            pack = __float_as_uint(q3.x);
            float mz = q3.y;
            bk = NBUCK - 1;
            if (mz < 1e30f) { bk = (int)(mz * 512.0f); bk = bk < 0 ? 0 : (bk > NBUCK-2 ? NBUCK-2 : bk); }
        }
        float key = (bk == NBUCK-1) ? 3e38f : (float)bk * (1.0f/512.0f);  // exact dyadic LB
        int pos = (int)atomicAdd(&s_cnt2[bk], 1u);
        sxb[pos] = make_uint2(pack, __float_as_uint(key));
        stb[pos] = (unsigned short)j;
    }
}

// ============ Kernel 2: tile raster, SPLIT blocks/tile, shared per-pixel z =======
// R23: barrier-free eval groups. R17-R21 pinned raster at 84-86us across four
// different bodies (issue cuts, chain cuts flat; R18's +2 barriers/group = +8us
// -> barrier count is the only knob that moved time). Fix: stage each group's
// 64 records ONE PER LANE in registers (4xfloat4, wave-uniform flow) and read
// entry i's fields via v_readlane in the eval loop. No sh[] LDS, NO per-group
// barriers -- waves run decoupled between chunk front-end and chunk-end reduce.
__global__ __launch_bounds__(256) void raster_kernel(
    const float4* __restrict__ rec, const uint2* __restrict__ sax,
    const unsigned short* __restrict__ stri, unsigned int* __restrict__ zbits,
    int F2)
{
#pragma clang fp contract(off)
    __shared__ float2 s_kb[256];               // (sort key, bbox-pack-as-float)
    __shared__ unsigned short s_list[256];
    __shared__ int s_wk[4], s_kk[4], s_wo[4];
    __shared__ int s_tot, s_kc;
    __shared__ float s_tzmax, s_red[4];
    int zz = blockIdx.z;
    int b = zz / SPLIT, sp = zz - b*SPLIT;
    int tc = blockIdx.x, tr = blockIdx.y;
    int tid = threadIdx.x, lane = tid & 63, wv = tid >> 6;
    int tx = tid & 15, ty = tid >> 4;
    int col = tc*16 + tx, row = tr*16 + ty;
    float X = gval(col), Y = gval(row);
    int pc0 = tc*16, pc1 = pc0+15, pr0 = tr*16, pr1 = pr0+15;
    int wvs = __builtin_amdgcn_readfirstlane(wv);   // wave-uniform -> SGPR
    int wr0 = pr0 + wvs*4, wr1 = wr0 + 3;           // this wave's 4-row strip
    // tile rect over pixel CENTERS, for bin-time edge culling
    float Xc = 0.5f*(gval(pc0) + gval(pc1));
    float Yc = 0.5f*(gval(pr0) + gval(pr1));
    const float hxr = 15.0f/256.0f, hyr = 15.0f/256.0f;
    const float4* rb = rec + (size_t)b * F2 * 4;
    const uint2* sxb = sax + (size_t)b * F2;
    const unsigned short* stb = stri + (size_t)b * F2;
    size_t pix = ((size_t)b*RASTN + row)*RASTN + col;
    unsigned int* zp_g = zbits + pix;
    float zmin = FARV;
    float pushed = FARV;     // min value known to already be in zbits[pix]
    if (tid == 0) s_tzmax = FARV;
    __syncthreads();
    int nch = (F2 + 256*SPLIT - 1) / (256*SPLIT);
    for (int c = 0; c < nch; ++c) {
        // rank interleaved at fine granularity: all splits converge on the front
        int s = (c*256 + tid)*SPLIT + sp;
        bool kp = false, sv = false; unsigned int tri = 0; float kf = 0.0f;
        unsigned int pkv = 0;
        if (s < F2) {
            uint2 a = sxb[s];
            kf = __uint_as_float(a.y);
            kp = !(kf > s_tzmax);                  // conservative early-z (key <= minz)
            if (kp) {
                int pk = (int)a.x;
                int ic0 = pk & 255, ic1 = (pk >> 8) & 255;
                int ir0 = (pk >> 16) & 255, ir1 = (pk >> 24) & 255;
                sv = (ic0 <= ic1) && (ic0 <= pc1) && (ic1 >= pc0) && (ir0 <= pr1) && (ir1 >= pr0);
                if (sv) {
                    tri = stb[s];
                    pkv = a.x;
                    // ---- conservative 3-edge rect cull (per-thread, parallel;
                    //      folded coeffs -> no sign factor) ----
                    float4 q0 = rb[(size_t)tri*4 + 0];
                    float4 q1 = rb[(size_t)tri*4 + 1];
                    float4 q2 = rb[(size_t)tri*4 + 2];
                    float a0 = q0.z, b0 = q0.w;
                    float a1 = q1.x, b1 = q1.y;
                    float xcd = Xc - q0.x, ycd = Yc - q0.y;
                    float e0c = (a0*xcd) + (b0*ycd);
                    float e1c = (a1*xcd) + (b1*ycd);
                    float den = q2.x;                  // folded: >= 0
                    float e2c = (den - e0c) - e1c;
                    float a2 = -(a0 + a1), b2 = -(b0 + b1);
                    float t0 = fabsf(a0)*hxr + fabsf(b0)*hyr;
                    float t1 = fabsf(a1)*hxr + fabsf(b1)*hyr;
                    float t2 = fabsf(a2)*hxr + fabsf(b2)*hyr;
                    float m0 = e0c + t0;
                    float m1 = e1c + t1;
                    float m2 = e2c + t2;
                    // relative margins swamp f32 eval error; cull only if provably
                    // every pixel center has a strictly negative barycentric
                    bool cull = (m0 < -1e-5f*(fabsf(e0c) + t0 + 1.0f))
                             || (m1 < -1e-5f*(fabsf(e1c) + t1 + 1.0f))
                             || (m2 < -1e-5f*(fabsf(e2c) + t2 + 1.0f));
                    if (cull) sv = false;
                }
            }
        }
        unsigned long long bs = __ballot(sv ? 1 : 0);
        unsigned long long bk = __ballot(kp ? 1 : 0);
        int pfx = __popcll(bs & ((1ull << lane) - 1ull));
        if (lane == 0) { s_wk[wv] = __popcll(bs); s_kk[wv] = __popcll(bk); }
        __syncthreads();
        if (tid == 0) {
            int acc = 0;
            for (int q = 0; q < 4; ++q) { s_wo[q] = acc; acc += s_wk[q]; }
            s_tot = acc;
            s_kc = s_kk[0] + s_kk[1] + s_kk[2] + s_kk[3];
        }
        __syncthreads();
        if (sv) {
            int pos = s_wo[wv] + pfx;
            s_list[pos] = (unsigned short)tri;
            s_kb[pos] = make_float2(kf, __uint_as_float(pkv));  // monotone keys
        }
        int kcnt = s_kc, n = s_tot;
        if (kcnt == 0) break;   // keys non-decreasing: all remaining > tzmax
        __syncthreads();        // s_list/s_kb visible to all waves
        // ---- barrier-free groups: per-lane register staging + readlane eval ----
        for (int g = 0; g < n; g += 64) {
            int cnt2 = (n - g) < 64 ? (n - g) : 64;
            int li = g + (lane < cnt2 ? lane : 0);       // guarded (no OOB rb read)
            float2 kbv = s_kb[li];                       // 2-way LDS, conflict-free
            unsigned int t4 = s_list[li];
            const float4* rp = rb + (size_t)t4*4;
            float4 r0 = rp[0];                           // lane l holds entry g+l
            float4 r1 = rp[1];
            float4 r2v = rp[2];
            float4 r3 = rp[3];
            float zg = __uint_as_float(__hip_atomic_load(
                zp_g, __ATOMIC_RELAXED, __HIP_MEMORY_SCOPE_AGENT));
            pushed = fminf(pushed, zg);
            zmin = fminf(zmin, zg);
            int vkey = __float_as_int(kbv.x);
            int vbb  = __float_as_int(kbv.y);
            for (int i = 0; i < cnt2; ++i) {
                // register-file loop head (readlane ~4cy, no memory op)
                float ky = __int_as_float(__builtin_amdgcn_readlane(vkey, i));
                if (ky > zmin) break;          // monotone: lane permanently done
                unsigned int pk = (unsigned int)__builtin_amdgcn_readlane(vbb, i);
                int ir0 = (int)((pk >> 16) & 255u), ir1 = (int)(pk >> 24);
                if (ir1 < wr0 || ir0 > wr1) continue;   // scalar row-strip reject
                int ic0 = (int)(pk & 255u), ic1 = (int)((pk >> 8) & 255u);
                if (col < ic0 || col > ic1 || row < ir0 || row > ir1) continue;
                float q0x = rl(r0.x,i), q0y = rl(r0.y,i);
                float q0z = rl(r0.z,i), q0w = rl(r0.w,i);
                float q1x = rl(r1.x,i), q1y = rl(r1.y,i), q1z = rl(r1.z,i);
                float xc = X - q0x;
                float yc = Y - q0y;
                float e0 = (q0z*xc) + (q0w*yc);    // folded w0 numerator (= s0)
                float e1 = (q1x*xc) + (q1y*yc);    // folded w1 numerator
                float rd = q1z;                    // rcp(dens), dens >= 0
                float w0a = e0*rd, w1a = e1*rd;    // approx w (filter only)
                float w2a = (1.0f - w0a) - w1a;
                float epsu = 1e-4f*((1.0f + fabsf(w0a)) + fabsf(w1a));
                if (e0 > -1e-30f && e1 > -1e-30f && w2a > -epsu) {
                    float q1w = rl(r1.w,i), q3z = rl(r3.z,i), q3w = rl(r3.w,i);
                    float inva = ((w0a*q1w) + (w1a*q3z)) + (w2a*q3w);
                    float zpa = __builtin_amdgcn_rcpf(inva);
                    bool clearly = (e0 > 0.0f) && (e1 > 0.0f) && (w2a > epsu) && (inva > 1e-6f);
                    // clearly-valid + approx-zp above zmin (w/ margin) provably
                    // cannot change the exact min -> skip the 6 IEEE divides
                    if (!clearly || zpa < zmin*1.001f) {
                        float dens = rl(r2v.x,i);
                        float q2y = rl(r2v.y,i), q2z = rl(r2v.z,i), q2w = rl(r2v.w,i);
                        float w0 = e0 / dens;      // (-e)/(-d) bit-exact == ref
                        float w1 = e1 / dens;
                        float w2 = (1.0f - w0) - w1;
                        float inv = ((w0 / q2y) + (w1 / q2z)) + (w2 / q2w);
                        if ((w0 >= 0.0f) && (w1 >= 0.0f) && (w2 >= 0.0f) && (inv > 1e-8f)) {
                            float zp = 1.0f / inv; // exact div == ref zp
                            zmin = fminf(zmin, zp);
                        }
                    }
                }
            }
            // ---- push improvement so other splits can skip their warm-up
            if (zmin < pushed) {
                atomicMin(zp_g, __float_as_uint(zmin));   // bit-monotone positive floats
                pushed = zmin;
            }
        }
        if (n > 0) {
            // tile zmax refresh: only shrinks -> stays a conservative upper bound
            float zx = zmin;
            for (int o = 32; o; o >>= 1) zx = fmaxf(zx, __shfl_xor(zx, o));
            if (lane == 0) s_red[wv] = zx;
        }
        __syncthreads();        // all waves done with s_list/s_kb + s_red ready
        if (n > 0 && tid == 0)
            s_tzmax = fminf(s_tzmax,
                fmaxf(fmaxf(s_red[0], s_red[1]), fmaxf(s_red[2], s_red[3])));
        __syncthreads();
    }
    if (zmin < pushed)
        atomicMin(zp_g, __float_as_uint(zmin));   // final publish
}

// ============ Kernel 3: per-batch minmax reduction + mask write (float4) =========
__global__ __launch_bounds__(256) void minmax_kernel(
    const float4* __restrict__ zbuf, float4* __restrict__ mask,
    unsigned int* __restrict__ mm, int npix)
{
    __shared__ float smx[4], smn[4];
    int b = blockIdx.y;
    size_t i4 = (((size_t)b * npix) >> 2) + (size_t)blockIdx.x * 256 + threadIdx.x;
    float4 z = zbuf[i4];
    float4 mk;
    mk.x = (z.x < FARV) ? 1.0f : 0.0f;
    mk.y = (z.y < FARV) ? 1.0f : 0.0f;
    mk.z = (z.z < FARV) ? 1.0f : 0.0f;
    mk.w = (z.w < FARV) ? 1.0f : 0.0f;
    mask[i4] = mk;                            // cover == any valid hit (z < FAR)
    float nbx = (z.x == FARV) ? 0.0f : z.x;   // (1-img_inf)*img
    float nby = (z.y == FARV) ? 0.0f : z.y;
    float nbz = (z.z == FARV) ? 0.0f : z.z;
    float nbw = (z.w == FARV) ? 0.0f : z.w;
    float vmx = fmaxf(fmaxf(nbx, nby), fmaxf(nbz, nbw));
    float vmn = fminf(fminf(z.x, z.y), fminf(z.z, z.w));
    int lane = threadIdx.x & 63, wv = threadIdx.x >> 6;
    for (int o = 32; o; o >>= 1) {
        vmx = fmaxf(vmx, __shfl_xor(vmx, o));
        vmn = fminf(vmn, __shfl_xor(vmn, o));
    }
    if (lane == 0) { smx[wv] = vmx; smn[wv] = vmn; }
    __syncthreads();
    if (threadIdx.x == 0) {
        float bmx = fmaxf(fmaxf(smx[0], smx[1]), fmaxf(smx[2], smx[3]));
        float bmn = fminf(fminf(smn[0], smn[1]), fminf(smn[2], smn[3]));
        atomicMax(mm + 2*b,     __float_as_uint(bmx));   // positive floats: bit-monotone
        atomicMin(mm + 2*b + 1, __float_as_uint(bmn));
    }
}

// ============ Kernel 4: normalize depth in place (float4) ========================
__global__ __launch_bounds__(256) void final_kernel(
    float4* __restrict__ zdep, const unsigned int* __restrict__ mm,
    int npix4, int total4)
{
#pragma clang fp contract(off)
    int idx = blockIdx.x*256 + threadIdx.x;
    if (idx >= total4) return;
    int b = idx / npix4;
    float mx = __uint_as_float(mm[2*b]);
    float mn = __uint_as_float(mm[2*b + 1]);
    float den = (mx - mn) + 1e-4f;
    float4 z = zdep[idx];
    float4 r;
    r.x = (mx - z.x) / den;
    r.y = (mx - z.y) / den;
    r.z = (mx - z.z) / den;
    r.w = (mx - z.w) / den;
    r.x = r.x < 0.0f ? 0.0f : (r.x > 1.0f ? 1.0f : r.x);
    r.y = r.y < 0.0f ? 0.0f : (r.y > 1.0f ? 1.0f : r.y);
    r.z = r.z < 0.0f ? 0.0f : (r.z > 1.0f ? 1.0f : r.z);
    r.w = r.w < 0.0f ? 0.0f : (r.w > 1.0f ? 1.0f : r.w);
    zdep[idx] = r;
}

extern "C" void kernel_launch(void* const* d_in, const int* in_sizes, int n_in,
                              void* d_out, int out_size, void* d_ws, size_t ws_size,
                              hipStream_t stream)
{
    const float* verts = (const float*)d_in[0];
    const int*   faces = (const int*)d_in[1];
    const float* Km    = (const float*)d_in[2];
    const float* Rm    = (const float*)d_in[3];
    const float* tm    = (const float*)d_in[4];
    const float* dm    = (const float*)d_in[5];
    float* out = (float*)d_out;

    int B  = in_sizes[2] / 9;          // intr is B*3*3
    int V  = in_sizes[0] / (3 * B);
    int F  = in_sizes[1] / (3 * B);
    int F2 = 2 * F;
    int npix = RASTN * RASTN;

    char* ws = (char*)d_ws;
    size_t off = 0;
    float4* rec = (float4*)(ws + off);
    off = (off + (size_t)B * F2 * 4 * sizeof(float4) + 255) & ~(size_t)255;
    uint2* sax = (uint2*)(ws + off);
    off = (off + (size_t)B * F2 * sizeof(uint2) + 255) & ~(size_t)255;
    unsigned short* stri = (unsigned short*)(ws + off);
    off = (off + (size_t)B * F2 * sizeof(unsigned short) + 255) & ~(size_t)255;
    float* uvzg = (float*)(ws + off);
    off = (off + (size_t)B * V * 3 * sizeof(float) + 255) & ~(size_t)255;
    unsigned int* mm = (unsigned int*)(ws + off);

    unsigned int* zbits = (unsigned int*)out;    // depth region doubles as zbuf
    float* mask = out + (size_t)B * npix;

    dim3 pgrid(B, NINITY);
    prep_sort_kernel<<<pgrid, 1024, 0, stream>>>(
        verts, faces, Km, Rm, tm, dm, rec, sax, stri, zbits, mm, uvzg,
        V, F, F2, B, npix);
    dim3 rgrid(16, 16, B * SPLIT);
    raster_kernel<<<rgrid, 256, 0, stream>>>(rec, sax, stri, zbits, F2);
    dim3 mgrid(npix / 1024, B);
    minmax_kernel<<<mgrid, 256, 0, stream>>>(
        (const float4*)zbits, (float4*)mask, mm, npix);
    int npix4 = npix >> 2;
    int total4 = B * npix4;
    final_kernel<<<(total4 + 255) / 256, 256, 0, stream>>>(
        (float4*)zbits, mm, npix4, total4);
}

// Round 10
// 160.738 us; speedup vs baseline: 1.0875x; 1.0765x over previous
//
#include <hip/hip_runtime.h>
#include <cstdint>

#define RASTN 256
#define FARV 10.0f
#define FARBITS 0x41200000u   // bits of 10.0f
#define SPLIT 4               // measured optimum (8 dup'd z-traffic, R22)
#define NBUCK 1024            // counting-sort buckets; width 1/512 (exact dyadic)
#define NINITY 8              // extra prep blocks per batch for zbuf memset

__device__ __forceinline__ float gval(int i) {
    // g = 2*(i+0.5)/256 - 1  -- exact in f32 (multiples of 1/256)
    return (2.0f * ((float)i + 0.5f)) / 256.0f - 1.0f;
}

// ============ Kernel 1: project + prep + counting-sort + inits (grid B x NINITY) =
// R24 rec layout (cull = 2 gathers instead of 3):
//   q0 = (cx, cy, a0, b0)        q1 = (a1, b1, dens, rd)
//   q2 = (ra, rbz, rc, minz)     q3 = (pack, za, zb, zc)
// R24 sax/stri layout: SPLIT-major -- sorted rank pos stored at
//   addr = (pos%SPLIT)*seg + pos/SPLIT, seg = F2c/SPLIT -> each raster block
// scans a CONTIGUOUS run (coalesced 8B loads; keys stay monotone per split).
__global__ __launch_bounds__(1024) void prep_sort_kernel(
    const float* __restrict__ verts, const int* __restrict__ faces,
    const float* __restrict__ Km, const float* __restrict__ Rm,
    const float* __restrict__ tm, const float* __restrict__ dm,
    float4* __restrict__ rec, uint2* __restrict__ sax, unsigned short* __restrict__ stri,
    unsigned int* __restrict__ zbits, unsigned int* __restrict__ mm,
    float* __restrict__ uvzg, int V, int F, int F2, int F2c, int B, int npix)
{
#pragma clang fp contract(off)
    __shared__ float s_uvz[1024*3];
    __shared__ unsigned int s_pk[4096];
    __shared__ unsigned short s_bk[4096];
    __shared__ unsigned int s_hist[NBUCK], s_cnt2[NBUCK];
    __shared__ unsigned int s_ws[16];
    int b = blockIdx.x, y = blockIdx.y, tid = threadIdx.x;
    int lane = tid & 63, wv16 = tid >> 6;
    // ---- parallel z-buffer init: each y-block memsets 1/NINITY of this batch ----
    uint4* zb4 = (uint4*)(zbits + (size_t)b * npix);
    int n4 = npix >> 2;
    int sl0 = (n4 * y) / NINITY, sl1 = (n4 * (y + 1)) / NINITY;
    for (int i = sl0 + tid; i < sl1; i += 1024)
        zb4[i] = make_uint4(FARBITS, FARBITS, FARBITS, FARBITS);
    if (y > 0) return;
    if (tid == 0) { mm[2*b] = 0u; mm[2*b+1] = FARBITS; }  // minmax accumulators
    for (int i = tid; i < NBUCK; i += 1024) s_hist[i] = 0u;
    int seg = F2c / SPLIT;
    uint2* sxb = sax + (size_t)b * F2c;
    unsigned short* stb = stri + (size_t)b * F2c;
    // ---- dead-key padding for ranks [F2, F2c) (sort last; never kept) ----------
    for (int p = F2 + tid; p < F2c; p += 1024) {
        int addr = (p % SPLIT) * seg + p / SPLIT;
        sxb[addr] = make_uint2(1u /*ic0=1>ic1=0: dead bbox*/, __float_as_uint(3e38f));
        stb[addr] = 0;
    }
    // ---- project (bit-exact replica of reference _project) ----
    bool inlds = (V <= 1024);
    const float* R = Rm + b*9; const float* K = Km + b*9;
    const float* t = tm + b*3; const float* d = dm + b*5;
    for (int v = tid; v < V; v += 1024) {
        float vx = verts[((size_t)b*V + v)*3+0];
        float vy = verts[((size_t)b*V + v)*3+1];
        float vz = verts[((size_t)b*V + v)*3+2];
        float cxm = ((vx*R[0] + vy*R[1]) + vz*R[2]) + t[0];
        float cym = ((vx*R[3] + vy*R[4]) + vz*R[5]) + t[1];
        float czm = ((vx*R[6] + vy*R[7]) + vz*R[8]) + t[2];
        float zd = czm + 1e-9f;
        float x_ = cxm / zd;
        float y_ = cym / zd;
        float k1 = d[0], k2 = d[1], p1 = d[2], p2 = d[3], k3 = d[4];
        float r2   = (x_*x_) + (y_*y_);
        float r2_2 = r2 * r2;
        float r2_3 = r2 * r2_2;
        float radial = ((1.0f + k1*r2) + k2*r2_2) + k3*r2_3;
        float x__ = ((x_*radial) + (((2.0f*p1)*x_)*y_)) + (p2*(r2 + 2.0f*(x_*x_)));
        float y__ = ((y_*radial) + (p1*(r2 + 2.0f*(y_*y_)))) + (((2.0f*p2)*x_)*y_);
        float up = ((x__*K[0]) + (y__*K[1])) + (1.0f*K[2]);
        float vp = ((x__*K[3]) + (y__*K[4])) + (1.0f*K[5]);
        vp = 256.0f - vp;
        float un = (2.0f*(up - 128.0f)) / 256.0f;
        float vn = (2.0f*(vp - 128.0f)) / 256.0f;
        if (inlds) { s_uvz[v*3+0]=un; s_uvz[v*3+1]=vn; s_uvz[v*3+2]=czm; }
        else { uvzg[((size_t)b*V+v)*3+0]=un; uvzg[((size_t)b*V+v)*3+1]=vn; uvzg[((size_t)b*V+v)*3+2]=czm; }
    }
    __syncthreads();
    const float* ub = inlds ? s_uvz : (uvzg + (size_t)b*V*3);
    const int* fb = faces + (size_t)b * F * 3;
    float4* rb = rec + (size_t)b * F2 * 4;
    bool stash = (F2 <= 4096);
    // ---- prep + histogram ----
    for (int j = tid; j < F2; j += 1024) {
        int i0, i1, i2;
        if (j < F) { i0 = fb[j*3+0]; i1 = fb[j*3+1]; i2 = fb[j*3+2]; }
        else { int jj = j - F; i0 = fb[jj*3+2]; i1 = fb[jj*3+1]; i2 = fb[jj*3+0]; }
        float ax = ub[i0*3+0], ay = ub[i0*3+1], az = ub[i0*3+2];
        float bx = ub[i1*3+0], by = ub[i1*3+1], bz = ub[i1*3+2];
        float cx = ub[i2*3+0], cy = ub[i2*3+1], cz = ub[i2*3+2];
        float den = (bx-ax)*(cy-ay) - (by-ay)*(cx-ax);
        bool ok = fabsf(den) > 1e-8f;
        float dens = ok ? den : 1.0f;
        bool alive = ok && (az > 1e-8f) && (bz > 1e-8f) && (cz > 1e-8f);
        float za = (az > 1e-8f) ? az : 1.0f;
        float zb = (bz > 1e-8f) ? bz : 1.0f;
        float zc = (cz > 1e-8f) ? cz : 1.0f;
        float mnx = fminf(ax, fminf(bx, cx));
        float mxx = fmaxf(ax, fmaxf(bx, cx));
        float mny = fminf(ay, fminf(by, cy));
        float mxy = fmaxf(ay, fmaxf(by, cy));
        float m = 1e-3f + 1e-6f*((fabsf(mnx)+fabsf(mxx))+(fabsf(mny)+fabsf(mxy)));
        mnx -= m; mxx += m; mny -= m; mxy += m;
        if (!(mxx >= -1.0f) || !(mnx <= 1.0f) || !(mxy >= -1.0f) || !(mny <= 1.0f)) alive = false;
        int ic0 = 1, ic1 = 0, ir0 = 1, ir1 = 0;
        float minz = 3e38f;
        if (alive) {
            float lx = fmaxf(mnx, -1.5f), hx = fminf(mxx, 1.5f);
            float ly = fmaxf(mny, -1.5f), hy = fminf(mxy, 1.5f);
            ic0 = (int)floorf((lx + 1.0f) * 128.0f - 0.5f);
            ic1 = (int)ceilf ((hx + 1.0f) * 128.0f - 0.5f);
            ir0 = (int)floorf((ly + 1.0f) * 128.0f - 0.5f);
            ir1 = (int)ceilf ((hy + 1.0f) * 128.0f - 0.5f);
            ic0 = ic0 < 0 ? 0 : ic0;  ir0 = ir0 < 0 ? 0 : ir0;
            ic1 = ic1 > 255 ? 255 : ic1;  ir1 = ir1 > 255 ? 255 : ir1;
            if (ic0 > ic1 || ir0 > ir1) { ic0 = 1; ic1 = 0; ir0 = 1; ir1 = 0; minz = 3e38f; }
            else minz = fminf(za, fminf(zb, zc)) * (1.0f - 4e-4f);  // conservative early-z key
        }
        float minzv = fminf(za, fminf(zb, zc));
        float maxzv = fmaxf(za, fmaxf(zb, zc));
        // ---- sign pre-fold: stored dens >= 0, edge coeffs negated to match.
        // (-e)/(-d) is bit-identical to e/d in IEEE -> exact path unchanged.
        float a0 = by - cy, b0 = cx - bx;
        float a1 = cy - ay, b1 = ax - cx;
        float densf = dens;
        if (dens < 0.0f) { a0 = -a0; b0 = -b0; a1 = -a1; b1 = -b1; densf = -dens; }
        float rd = __builtin_amdgcn_rcpf(densf);
        float ra, rbz, rc;
        if (minzv > 1e-2f && maxzv < 100.0f * minzv) {
            ra  = __builtin_amdgcn_rcpf(za);
            rbz = __builtin_amdgcn_rcpf(zb);
            rc  = __builtin_amdgcn_rcpf(zc);
        } else {
            ra = rbz = rc = __builtin_huge_valf();   // filters disabled -> exact path
        }
        unsigned int pack = (unsigned int)(ic0 | (ic1 << 8) | (ir0 << 16) | (ir1 << 24));
        int bk = NBUCK - 1;                          // dead -> last bucket (huge key)
        if (minz < 1e30f) {
            bk = (int)(minz * 512.0f);               // floor; bucket LB = bk/512 exact
            bk = bk < 0 ? 0 : (bk > NBUCK-2 ? NBUCK-2 : bk);
        }
        size_t base = (size_t)j * 4;
        rb[base+0] = make_float4(cx, cy, a0, b0);
        rb[base+1] = make_float4(a1, b1, densf, rd);
        rb[base+2] = make_float4(ra, rbz, rc, minz);
        rb[base+3] = make_float4(__uint_as_float(pack), za, zb, zc);
        atomicAdd(&s_hist[bk], 1u);
        if (stash) { s_pk[j] = pack; s_bk[j] = (unsigned short)bk; }
    }
    __syncthreads();
    // ---- exclusive prefix over NBUCK buckets: shfl wave-scan, 3 barriers --------
    {
        unsigned int h = s_hist[tid];        // NBUCK == blockDim == 1024
        unsigned int v = h;
        for (int o = 1; o < 64; o <<= 1) {
            unsigned int tsh = __shfl_up(v, o, 64);
            if (lane >= o) v += tsh;
        }
        if (lane == 63) s_ws[wv16] = v;      // 16 wave totals
        __syncthreads();
        if (tid < 16) {
            unsigned int w = s_ws[tid];
            for (int o = 1; o < 16; o <<= 1) {
                unsigned int tsh = __shfl_up(w, o, 64);
                if (tid >= o) w += tsh;
            }
            s_ws[tid] = w;                   // inclusive wave-total scan
        }
        __syncthreads();
        unsigned int add = (wv16 > 0) ? s_ws[wv16 - 1] : 0u;
        s_cnt2[tid] = v + add - h;           // exclusive offsets
    }
    __syncthreads();
    // ---- scatter (split-major addressing; key = bucket LB -> conservative) ------
    for (int j = tid; j < F2; j += 1024) {
        unsigned int pack; int bk;
        if (stash) { pack = s_pk[j]; bk = (int)s_bk[j]; }
        else {
            float4 q3 = rb[(size_t)j*4+3];
            float4 q2 = rb[(size_t)j*4+2];
            pack = __float_as_uint(q3.x);
            float mz = q2.w;
            bk = NBUCK - 1;
            if (mz < 1e30f) { bk = (int)(mz * 512.0f); bk = bk < 0 ? 0 : (bk > NBUCK-2 ? NBUCK-2 : bk); }
        }
        float key = (bk == NBUCK-1) ? 3e38f : (float)bk * (1.0f/512.0f);  // exact dyadic LB
        int pos = (int)atomicAdd(&s_cnt2[bk], 1u);
        int addr = (pos % SPLIT) * seg + pos / SPLIT;    // split-major
        sxb[addr] = make_uint2(pack, __float_as_uint(key));
        stb[addr] = (unsigned short)j;
    }
}

// ============ Kernel 2: tile raster, SPLIT blocks/tile, shared per-pixel z =======
// R24 = R21 body (best: 160.5 total) + gather-line cuts. Hypothesis after 5
// flat/regressed rounds: TA-throughput-bound on divergent gathers (invisible
// to SQ counters). (1) split-major sax -> front-end scan is contiguous
// (8 lines/wave vs 32); (2) rec remap -> cull reads 2 records, not 3.
__global__ __launch_bounds__(256) void raster_kernel(
    const float4* __restrict__ rec, const uint2* __restrict__ sax,
    const unsigned short* __restrict__ stri, unsigned int* __restrict__ zbits,
    int F2, int F2c)
{
#pragma clang fp contract(off)
    __shared__ float4 sh[256];                 // 64 tris x 4 records
    __shared__ float2 s_kb[256];               // (sort key, bbox-pack-as-float)
    __shared__ unsigned short s_list[256];
    __shared__ int s_wk[4], s_kk[4], s_wo[4];
    __shared__ int s_tot, s_kc;
    __shared__ float s_tzmax, s_red[4];
    int zz = blockIdx.z;
    int b = zz / SPLIT, sp = zz - b*SPLIT;
    int tc = blockIdx.x, tr = blockIdx.y;
    int tid = threadIdx.x, lane = tid & 63, wv = tid >> 6;
    int tx = tid & 15, ty = tid >> 4;
    int col = tc*16 + tx, row = tr*16 + ty;
    float X = gval(col), Y = gval(row);
    int pc0 = tc*16, pc1 = pc0+15, pr0 = tr*16, pr1 = pr0+15;
    int wvs = __builtin_amdgcn_readfirstlane(wv);   // wave-uniform -> SGPR
    int wr0 = pr0 + wvs*4, wr1 = wr0 + 3;           // this wave's 4-row strip
    // tile rect over pixel CENTERS, for bin-time edge culling
    float Xc = 0.5f*(gval(pc0) + gval(pc1));
    float Yc = 0.5f*(gval(pr0) + gval(pr1));
    const float hxr = 15.0f/256.0f, hyr = 15.0f/256.0f;
    int seg = F2c / SPLIT;
    const float4* rb = rec + (size_t)b * F2 * 4;
    const uint2* sxb = sax + (size_t)b * F2c + (size_t)sp * seg;     // contiguous run
    const unsigned short* stb = stri + (size_t)b * F2c + (size_t)sp * seg;
    size_t pix = ((size_t)b*RASTN + row)*RASTN + col;
    unsigned int* zp_g = zbits + pix;
    float zmin = FARV;
    float pushed = FARV;     // min value known to already be in zbits[pix]
    if (tid == 0) s_tzmax = FARV;
    __syncthreads();
    int nch = (seg + 255) / 256;
    for (int c = 0; c < nch; ++c) {
        // coalesced scan of this split's sorted sub-stream (keys monotone)
        int s = c*256 + tid;
        bool kp = false, sv = false; unsigned int tri = 0; float kf = 0.0f;
        unsigned int pkv = 0;
        if (s < seg) {
            uint2 a = sxb[s];
            kf = __uint_as_float(a.y);
            kp = !(kf > s_tzmax);                  // conservative early-z (key <= minz)
            if (kp) {
                int pk = (int)a.x;
                int ic0 = pk & 255, ic1 = (pk >> 8) & 255;
                int ir0 = (pk >> 16) & 255, ir1 = (pk >> 24) & 255;
                sv = (ic0 <= ic1) && (ic0 <= pc1) && (ic1 >= pc0) && (ir0 <= pr1) && (ir1 >= pr0);
                if (sv) {
                    tri = stb[s];
                    pkv = a.x;
                    // ---- conservative 3-edge rect cull (2 gathers: q0,q1) ----
                    float4 q0 = rb[(size_t)tri*4 + 0];
                    float4 q1 = rb[(size_t)tri*4 + 1];
                    float a0 = q0.z, b0 = q0.w;
                    float a1 = q1.x, b1 = q1.y;
                    float xcd = Xc - q0.x, ycd = Yc - q0.y;
                    float e0c = (a0*xcd) + (b0*ycd);
                    float e1c = (a1*xcd) + (b1*ycd);
                    float den = q1.z;                  // folded: >= 0
                    float e2c = (den - e0c) - e1c;
                    float a2 = -(a0 + a1), b2 = -(b0 + b1);
                    float t0 = fabsf(a0)*hxr + fabsf(b0)*hyr;
                    float t1 = fabsf(a1)*hxr + fabsf(b1)*hyr;
                    float t2 = fabsf(a2)*hxr + fabsf(b2)*hyr;
                    float m0 = e0c + t0;
                    float m1 = e1c + t1;
                    float m2 = e2c + t2;
                    // relative margins swamp f32 eval error; cull only if provably
                    // every pixel center has a strictly negative barycentric
                    bool cull = (m0 < -1e-5f*(fabsf(e0c) + t0 + 1.0f))
                             || (m1 < -1e-5f*(fabsf(e1c) + t1 + 1.0f))
                             || (m2 < -1e-5f*(fabsf(e2c) + t2 + 1.0f));
                    if (cull) sv = false;
                }
            }
        }
        unsigned long long bs = __ballot(sv ? 1 : 0);
        unsigned long long bk = __ballot(kp ? 1 : 0);
        int pfx = __popcll(bs & ((1ull << lane) - 1ull));
        if (lane == 0) { s_wk[wv] = __popcll(bs); s_kk[wv] = __popcll(bk); }
        __syncthreads();
        if (tid == 0) {
            int acc = 0;
            for (int q = 0; q < 4; ++q) { s_wo[q] = acc; acc += s_wk[q]; }
            s_tot = acc;
            s_kc = s_kk[0] + s_kk[1] + s_kk[2] + s_kk[3];
        }
        __syncthreads();
        if (sv) {
            int pos = s_wo[wv] + pfx;
            s_list[pos] = (unsigned short)tri;
            s_kb[pos] = make_float2(kf, __uint_as_float(pkv));  // monotone keys
        }
        int kcnt = s_kc, n = s_tot;
        if (kcnt == 0) break;   // keys non-decreasing: all remaining > tzmax
        for (int g = 0; g < n; g += 64) {
            __syncthreads();
            // issue shared-z pull + per-lane (key,bbox) copy FIRST: the staging
            // barrier's implicit waits absorb their latency.
            float zg = __uint_as_float(__hip_atomic_load(
                zp_g, __ATOMIC_RELAXED, __HIP_MEMORY_SCOPE_AGENT));
            float2 kbv = s_kb[g + lane];   // lane l holds pair g+l (2-way, free)
            int cnt2 = (n - g) < 64 ? (n - g) : 64;
            if (tid < cnt2*4) {
                unsigned int t4 = s_list[g + (tid >> 2)];
                sh[tid] = rb[(size_t)t4*4 + (tid & 3)];
            }
            __syncthreads();
            pushed = fminf(pushed, zg);
            zmin = fminf(zmin, zg);
            int vkey = __float_as_int(kbv.x);
            int vbb  = __float_as_int(kbv.y);
            for (int i = 0; i < cnt2; ++i) {
                // register-file loop head: readlane (~4cy) replaces ds_read_b64
                float ky = __int_as_float(__builtin_amdgcn_readlane(vkey, i));
                if (ky > zmin) break;          // monotone: lane permanently done
                unsigned int pk = (unsigned int)__builtin_amdgcn_readlane(vbb, i);
                int ir0 = (int)((pk >> 16) & 255u), ir1 = (int)(pk >> 24);
                if (ir1 < wr0 || ir0 > wr1) continue;   // scalar row-strip reject
                int ic0 = (int)(pk & 255u), ic1 = (int)((pk >> 8) & 255u);
                if (col < ic0 || col > ic1 || row < ir0 || row > ir1) continue;
                float4 q0 = sh[i*4+0];
                float4 q1 = sh[i*4+1];
                float xc = X - q0.x;
                float yc = Y - q0.y;
                float e0 = (q0.z*xc) + (q0.w*yc);  // folded w0 numerator (= s0)
                float e1 = (q1.x*xc) + (q1.y*yc);  // folded w1 numerator
                float rd = q1.w;                   // rcp(dens), dens >= 0
                float w0a = e0*rd, w1a = e1*rd;    // approx w (filter only)
                float w2a = (1.0f - w0a) - w1a;
                float epsu = 1e-4f*((1.0f + fabsf(w0a)) + fabsf(w1a));
                if (e0 > -1e-30f && e1 > -1e-30f && w2a > -epsu) {
                    float4 q2 = sh[i*4+2];         // (ra, rbz, rc, minz)
                    float inva = ((w0a*q2.x) + (w1a*q2.y)) + (w2a*q2.z);
                    float zpa = __builtin_amdgcn_rcpf(inva);
                    bool clearly = (e0 > 0.0f) && (e1 > 0.0f) && (w2a > epsu) && (inva > 1e-6f);
                    // clearly-valid + approx-zp above zmin (w/ margin) provably
                    // cannot change the exact min -> skip the 6 IEEE divides
                    if (!clearly || zpa < zmin*1.001f) {
                        float4 q3 = sh[i*4+3];     // (pack, za, zb, zc)
                        float dens = q1.z;
                        float w0 = e0 / dens;      // (-e)/(-d) bit-exact == ref
                        float w1 = e1 / dens;
                        float w2 = (1.0f - w0) - w1;
                        float inv = ((w0 / q3.y) + (w1 / q3.z)) + (w2 / q3.w);
                        if ((w0 >= 0.0f) && (w1 >= 0.0f) && (w2 >= 0.0f) && (inv > 1e-8f)) {
                            float zp = 1.0f / inv; // exact div == ref zp
                            zmin = fminf(zmin, zp);
                        }
                    }
                }
            }
            // ---- push improvement so other splits can skip their warm-up
            if (zmin < pushed) {
                atomicMin(zp_g, __float_as_uint(zmin));   // bit-monotone positive floats
                pushed = zmin;
            }
        }
        if (n > 0) {
            // tile zmax refresh: only shrinks -> stays a conservative upper bound
            float zx = zmin;
            for (int o = 32; o; o >>= 1) zx = fmaxf(zx, __shfl_xor(zx, o));
            if (lane == 0) s_red[wv] = zx;
        }
        __syncthreads();
        if (n > 0 && tid == 0)
            s_tzmax = fminf(s_tzmax,
                fmaxf(fmaxf(s_red[0], s_red[1]), fmaxf(s_red[2], s_red[3])));
        __syncthreads();
    }
    if (zmin < pushed)
        atomicMin(zp_g, __float_as_uint(zmin));   // final publish
}

// ============ Kernel 3: per-batch minmax reduction + mask write (float4) =========
__global__ __launch_bounds__(256) void minmax_kernel(
    const float4* __restrict__ zbuf, float4* __restrict__ mask,
    unsigned int* __restrict__ mm, int npix)
{
    __shared__ float smx[4], smn[4];
    int b = blockIdx.y;
    size_t i4 = (((size_t)b * npix) >> 2) + (size_t)blockIdx.x * 256 + threadIdx.x;
    float4 z = zbuf[i4];
    float4 mk;
    mk.x = (z.x < FARV) ? 1.0f : 0.0f;
    mk.y = (z.y < FARV) ? 1.0f : 0.0f;
    mk.z = (z.z < FARV) ? 1.0f : 0.0f;
    mk.w = (z.w < FARV) ? 1.0f : 0.0f;
    mask[i4] = mk;                            // cover == any valid hit (z < FAR)
    float nbx = (z.x == FARV) ? 0.0f : z.x;   // (1-img_inf)*img
    float nby = (z.y == FARV) ? 0.0f : z.y;
    float nbz = (z.z == FARV) ? 0.0f : z.z;
    float nbw = (z.w == FARV) ? 0.0f : z.w;
    float vmx = fmaxf(fmaxf(nbx, nby), fmaxf(nbz, nbw));
    float vmn = fminf(fminf(z.x, z.y), fminf(z.z, z.w));
    int lane = threadIdx.x & 63, wv = threadIdx.x >> 6;
    for (int o = 32; o; o >>= 1) {
        vmx = fmaxf(vmx, __shfl_xor(vmx, o));
        vmn = fminf(vmn, __shfl_xor(vmn, o));
    }
    if (lane == 0) { smx[wv] = vmx; smn[wv] = vmn; }
    __syncthreads();
    if (threadIdx.x == 0) {
        float bmx = fmaxf(fmaxf(smx[0], smx[1]), fmaxf(smx[2], smx[3]));
        float bmn = fminf(fminf(smn[0], smn[1]), fminf(smn[2], smn[3]));
        atomicMax(mm + 2*b,     __float_as_uint(bmx));   // positive floats: bit-monotone
        atomicMin(mm + 2*b + 1, __float_as_uint(bmn));
    }
}

// ============ Kernel 4: normalize depth in place (float4) ========================
__global__ __launch_bounds__(256) void final_kernel(
    float4* __restrict__ zdep, const unsigned int* __restrict__ mm,
    int npix4, int total4)
{
#pragma clang fp contract(off)
    int idx = blockIdx.x*256 + threadIdx.x;
    if (idx >= total4) return;
    int b = idx / npix4;
    float mx = __uint_as_float(mm[2*b]);
    float mn = __uint_as_float(mm[2*b + 1]);
    float den = (mx - mn) + 1e-4f;
    float4 z = zdep[idx];
    float4 r;
    r.x = (mx - z.x) / den;
    r.y = (mx - z.y) / den;
    r.z = (mx - z.z) / den;
    r.w = (mx - z.w) / den;
    r.x = r.x < 0.0f ? 0.0f : (r.x > 1.0f ? 1.0f : r.x);
    r.y = r.y < 0.0f ? 0.0f : (r.y > 1.0f ? 1.0f : r.y);
    r.z = r.z < 0.0f ? 0.0f : (r.z > 1.0f ? 1.0f : r.z);
    r.w = r.w < 0.0f ? 0.0f : (r.w > 1.0f ? 1.0f : r.w);
    zdep[idx] = r;
}

extern "C" void kernel_launch(void* const* d_in, const int* in_sizes, int n_in,
                              void* d_out, int out_size, void* d_ws, size_t ws_size,
                              hipStream_t stream)
{
    const float* verts = (const float*)d_in[0];
    const int*   faces = (const int*)d_in[1];
    const float* Km    = (const float*)d_in[2];
    const float* Rm    = (const float*)d_in[3];
    const float* tm    = (const float*)d_in[4];
    const float* dm    = (const float*)d_in[5];
    float* out = (float*)d_out;

    int B  = in_sizes[2] / 9;          // intr is B*3*3
    int V  = in_sizes[0] / (3 * B);
    int F  = in_sizes[1] / (3 * B);
    int F2 = 2 * F;
    int F2c = ((F2 + SPLIT - 1) / SPLIT) * SPLIT;   // padded to SPLIT multiple
    int npix = RASTN * RASTN;

    char* ws = (char*)d_ws;
    size_t off = 0;
    float4* rec = (float4*)(ws + off);
    off = (off + (size_t)B * F2 * 4 * sizeof(float4) + 255) & ~(size_t)255;
    uint2* sax = (uint2*)(ws + off);
    off = (off + (size_t)B * F2c * sizeof(uint2) + 255) & ~(size_t)255;
    unsigned short* stri = (unsigned short*)(ws + off);
    off = (off + (size_t)B * F2c * sizeof(unsigned short) + 255) & ~(size_t)255;
    float* uvzg = (float*)(ws + off);
    off = (off + (size_t)B * V * 3 * sizeof(float) + 255) & ~(size_t)255;
    unsigned int* mm = (unsigned int*)(ws + off);

    unsigned int* zbits = (unsigned int*)out;    // depth region doubles as zbuf
    float* mask = out + (size_t)B * npix;

    dim3 pgrid(B, NINITY);
    prep_sort_kernel<<<pgrid, 1024, 0, stream>>>(
        verts, faces, Km, Rm, tm, dm, rec, sax, stri, zbits, mm, uvzg,
        V, F, F2, F2c, B, npix);
    dim3 rgrid(16, 16, B * SPLIT);
    raster_kernel<<<rgrid, 256, 0, stream>>>(rec, sax, stri, zbits, F2, F2c);
    dim3 mgrid(npix / 1024, B);
    minmax_kernel<<<mgrid, 256, 0, stream>>>(
        (const float4*)zbits, (float4*)mask, mm, npix);
    int npix4 = npix >> 2;
    int total4 = B * npix4;
    final_kernel<<<(total4 + 255) / 256, 256, 0, stream>>>(
        (float4*)zbits, mm, npix4, total4);
}

// Round 11
// 160.302 us; speedup vs baseline: 1.0905x; 1.0027x over previous
//
#include <hip/hip_runtime.h>
#include <cstdint>

#define RASTN 256
#define FARV 10.0f
#define FARBITS 0x41200000u   // bits of 10.0f
#define SPLIT 4               // measured optimum (8 dup'd z-traffic, R22)
#define NBUCK 1024            // counting-sort buckets; width 1/512 (exact dyadic)
#define NINITY 8              // extra prep blocks per batch for zbuf memset

__device__ __forceinline__ float gval(int i) {
    // g = 2*(i+0.5)/256 - 1  -- exact in f32 (multiples of 1/256)
    return (2.0f * ((float)i + 0.5f)) / 256.0f - 1.0f;
}

// ============ Kernel 1: project + prep + counting-sort + inits (grid B x NINITY) =
// rec layout: q0 = (cx, cy, a0, b0)   q1 = (a1, b1, dens, rd)
//             q2 = (ra, rbz, rc, minz) q3 = (pack, za, zb, zc)
// sax/stri layout: SPLIT-major (coalesced per-block scan, keys monotone/split).
__global__ __launch_bounds__(1024) void prep_sort_kernel(
    const float* __restrict__ verts, const int* __restrict__ faces,
    const float* __restrict__ Km, const float* __restrict__ Rm,
    const float* __restrict__ tm, const float* __restrict__ dm,
    float4* __restrict__ rec, uint2* __restrict__ sax, unsigned short* __restrict__ stri,
    unsigned int* __restrict__ zbits, unsigned int* __restrict__ mm,
    float* __restrict__ uvzg, int V, int F, int F2, int F2c, int B, int npix)
{
#pragma clang fp contract(off)
    __shared__ float s_uvz[1024*3];
    __shared__ unsigned int s_pk[4096];
    __shared__ unsigned short s_bk[4096];
    __shared__ unsigned int s_hist[NBUCK], s_cnt2[NBUCK];
    __shared__ unsigned int s_ws[16];
    int b = blockIdx.x, y = blockIdx.y, tid = threadIdx.x;
    int lane = tid & 63, wv16 = tid >> 6;
    // ---- parallel z-buffer init: each y-block memsets 1/NINITY of this batch ----
    uint4* zb4 = (uint4*)(zbits + (size_t)b * npix);
    int n4 = npix >> 2;
    int sl0 = (n4 * y) / NINITY, sl1 = (n4 * (y + 1)) / NINITY;
    for (int i = sl0 + tid; i < sl1; i += 1024)
        zb4[i] = make_uint4(FARBITS, FARBITS, FARBITS, FARBITS);
    if (y > 0) return;
    if (tid == 0) { mm[2*b] = 0u; mm[2*b+1] = FARBITS; }  // minmax accumulators
    for (int i = tid; i < NBUCK; i += 1024) s_hist[i] = 0u;
    int seg = F2c / SPLIT;
    uint2* sxb = sax + (size_t)b * F2c;
    unsigned short* stb = stri + (size_t)b * F2c;
    // ---- dead-key padding for ranks [F2, F2c) (sort last; never kept) ----------
    for (int p = F2 + tid; p < F2c; p += 1024) {
        int addr = (p % SPLIT) * seg + p / SPLIT;
        sxb[addr] = make_uint2(1u /*ic0=1>ic1=0: dead bbox*/, __float_as_uint(3e38f));
        stb[addr] = 0;
    }
    // ---- project (bit-exact replica of reference _project) ----
    bool inlds = (V <= 1024);
    const float* R = Rm + b*9; const float* K = Km + b*9;
    const float* t = tm + b*3; const float* d = dm + b*5;
    for (int v = tid; v < V; v += 1024) {
        float vx = verts[((size_t)b*V + v)*3+0];
        float vy = verts[((size_t)b*V + v)*3+1];
        float vz = verts[((size_t)b*V + v)*3+2];
        float cxm = ((vx*R[0] + vy*R[1]) + vz*R[2]) + t[0];
        float cym = ((vx*R[3] + vy*R[4]) + vz*R[5]) + t[1];
        float czm = ((vx*R[6] + vy*R[7]) + vz*R[8]) + t[2];
        float zd = czm + 1e-9f;
        float x_ = cxm / zd;
        float y_ = cym / zd;
        float k1 = d[0], k2 = d[1], p1 = d[2], p2 = d[3], k3 = d[4];
        float r2   = (x_*x_) + (y_*y_);
        float r2_2 = r2 * r2;
        float r2_3 = r2 * r2_2;
        float radial = ((1.0f + k1*r2) + k2*r2_2) + k3*r2_3;
        float x__ = ((x_*radial) + (((2.0f*p1)*x_)*y_)) + (p2*(r2 + 2.0f*(x_*x_)));
        float y__ = ((y_*radial) + (p1*(r2 + 2.0f*(y_*y_)))) + (((2.0f*p2)*x_)*y_);
        float up = ((x__*K[0]) + (y__*K[1])) + (1.0f*K[2]);
        float vp = ((x__*K[3]) + (y__*K[4])) + (1.0f*K[5]);
        vp = 256.0f - vp;
        float un = (2.0f*(up - 128.0f)) / 256.0f;
        float vn = (2.0f*(vp - 128.0f)) / 256.0f;
        if (inlds) { s_uvz[v*3+0]=un; s_uvz[v*3+1]=vn; s_uvz[v*3+2]=czm; }
        else { uvzg[((size_t)b*V+v)*3+0]=un; uvzg[((size_t)b*V+v)*3+1]=vn; uvzg[((size_t)b*V+v)*3+2]=czm; }
    }
    __syncthreads();
    const float* ub = inlds ? s_uvz : (uvzg + (size_t)b*V*3);
    const int* fb = faces + (size_t)b * F * 3;
    float4* rb = rec + (size_t)b * F2 * 4;
    bool stash = (F2 <= 4096);
    // ---- prep + histogram ----
    for (int j = tid; j < F2; j += 1024) {
        int i0, i1, i2;
        if (j < F) { i0 = fb[j*3+0]; i1 = fb[j*3+1]; i2 = fb[j*3+2]; }
        else { int jj = j - F; i0 = fb[jj*3+2]; i1 = fb[jj*3+1]; i2 = fb[jj*3+0]; }
        float ax = ub[i0*3+0], ay = ub[i0*3+1], az = ub[i0*3+2];
        float bx = ub[i1*3+0], by = ub[i1*3+1], bz = ub[i1*3+2];
        float cx = ub[i2*3+0], cy = ub[i2*3+1], cz = ub[i2*3+2];
        float den = (bx-ax)*(cy-ay) - (by-ay)*(cx-ax);
        bool ok = fabsf(den) > 1e-8f;
        float dens = ok ? den : 1.0f;
        bool alive = ok && (az > 1e-8f) && (bz > 1e-8f) && (cz > 1e-8f);
        float za = (az > 1e-8f) ? az : 1.0f;
        float zb = (bz > 1e-8f) ? bz : 1.0f;
        float zc = (cz > 1e-8f) ? cz : 1.0f;
        float mnx = fminf(ax, fminf(bx, cx));
        float mxx = fmaxf(ax, fmaxf(bx, cx));
        float mny = fminf(ay, fminf(by, cy));
        float mxy = fmaxf(ay, fmaxf(by, cy));
        float m = 1e-3f + 1e-6f*((fabsf(mnx)+fabsf(mxx))+(fabsf(mny)+fabsf(mxy)));
        mnx -= m; mxx += m; mny -= m; mxy += m;
        if (!(mxx >= -1.0f) || !(mnx <= 1.0f) || !(mxy >= -1.0f) || !(mny <= 1.0f)) alive = false;
        int ic0 = 1, ic1 = 0, ir0 = 1, ir1 = 0;
        float minz = 3e38f;
        if (alive) {
            float lx = fmaxf(mnx, -1.5f), hx = fminf(mxx, 1.5f);
            float ly = fmaxf(mny, -1.5f), hy = fminf(mxy, 1.5f);
            ic0 = (int)floorf((lx + 1.0f) * 128.0f - 0.5f);
            ic1 = (int)ceilf ((hx + 1.0f) * 128.0f - 0.5f);
            ir0 = (int)floorf((ly + 1.0f) * 128.0f - 0.5f);
            ir1 = (int)ceilf ((hy + 1.0f) * 128.0f - 0.5f);
            ic0 = ic0 < 0 ? 0 : ic0;  ir0 = ir0 < 0 ? 0 : ir0;
            ic1 = ic1 > 255 ? 255 : ic1;  ir1 = ir1 > 255 ? 255 : ir1;
            if (ic0 > ic1 || ir0 > ir1) { ic0 = 1; ic1 = 0; ir0 = 1; ir1 = 0; minz = 3e38f; }
            else minz = fminf(za, fminf(zb, zc)) * (1.0f - 4e-4f);  // conservative early-z key
        }
        float minzv = fminf(za, fminf(zb, zc));
        float maxzv = fmaxf(za, fmaxf(zb, zc));
        // ---- sign pre-fold: stored dens >= 0, edge coeffs negated to match.
        // (-e)/(-d) is bit-identical to e/d in IEEE -> exact path unchanged.
        float a0 = by - cy, b0 = cx - bx;
        float a1 = cy - ay, b1 = ax - cx;
        float densf = dens;
        if (dens < 0.0f) { a0 = -a0; b0 = -b0; a1 = -a1; b1 = -b1; densf = -dens; }
        float rd = __builtin_amdgcn_rcpf(densf);
        float ra, rbz, rc;
        if (minzv > 1e-2f && maxzv < 100.0f * minzv) {
            ra  = __builtin_amdgcn_rcpf(za);
            rbz = __builtin_amdgcn_rcpf(zb);
            rc  = __builtin_amdgcn_rcpf(zc);
        } else {
            ra = rbz = rc = __builtin_huge_valf();   // filters disabled -> exact path
        }
        unsigned int pack = (unsigned int)(ic0 | (ic1 << 8) | (ir0 << 16) | (ir1 << 24));
        int bk = NBUCK - 1;                          // dead -> last bucket (huge key)
        if (minz < 1e30f) {
            bk = (int)(minz * 512.0f);               // floor; bucket LB = bk/512 exact
            bk = bk < 0 ? 0 : (bk > NBUCK-2 ? NBUCK-2 : bk);
        }
        size_t base = (size_t)j * 4;
        rb[base+0] = make_float4(cx, cy, a0, b0);
        rb[base+1] = make_float4(a1, b1, densf, rd);
        rb[base+2] = make_float4(ra, rbz, rc, minz);
        rb[base+3] = make_float4(__uint_as_float(pack), za, zb, zc);
        atomicAdd(&s_hist[bk], 1u);
        if (stash) { s_pk[j] = pack; s_bk[j] = (unsigned short)bk; }
    }
    __syncthreads();
    // ---- exclusive prefix over NBUCK buckets: shfl wave-scan, 3 barriers --------
    {
        unsigned int h = s_hist[tid];        // NBUCK == blockDim == 1024
        unsigned int v = h;
        for (int o = 1; o < 64; o <<= 1) {
            unsigned int tsh = __shfl_up(v, o, 64);
            if (lane >= o) v += tsh;
        }
        if (lane == 63) s_ws[wv16] = v;      // 16 wave totals
        __syncthreads();
        if (tid < 16) {
            unsigned int w = s_ws[tid];
            for (int o = 1; o < 16; o <<= 1) {
                unsigned int tsh = __shfl_up(w, o, 64);
                if (tid >= o) w += tsh;
            }
            s_ws[tid] = w;                   // inclusive wave-total scan
        }
        __syncthreads();
        unsigned int add = (wv16 > 0) ? s_ws[wv16 - 1] : 0u;
        s_cnt2[tid] = v + add - h;           // exclusive offsets
    }
    __syncthreads();
    // ---- scatter (split-major addressing; key = bucket LB -> conservative) ------
    for (int j = tid; j < F2; j += 1024) {
        unsigned int pack; int bk;
        if (stash) { pack = s_pk[j]; bk = (int)s_bk[j]; }
        else {
            float4 q3 = rb[(size_t)j*4+3];
            float4 q2 = rb[(size_t)j*4+2];
            pack = __float_as_uint(q3.x);
            float mz = q2.w;
            bk = NBUCK - 1;
            if (mz < 1e30f) { bk = (int)(mz * 512.0f); bk = bk < 0 ? 0 : (bk > NBUCK-2 ? NBUCK-2 : bk); }
        }
        float key = (bk == NBUCK-1) ? 3e38f : (float)bk * (1.0f/512.0f);  // exact dyadic LB
        int pos = (int)atomicAdd(&s_cnt2[bk], 1u);
        int addr = (pos % SPLIT) * seg + pos / SPLIT;    // split-major
        sxb[addr] = make_uint2(pack, __float_as_uint(key));
        stb[addr] = (unsigned short)j;
    }
}

// ============ Kernel 2: tile raster, SPLIT blocks/tile, shared per-pixel z =======
// R25 = R24 + HIERARCHICAL-Z at the front-end. Six flat rounds showed time is
// invariant to per-entry cost -> the binder is kept-entry COUNT n. Global-minz
// keys are toothless for huge triangles (minz << z produced over any one tile).
// New: per-(tile,entry) conservative z lower bound from the cull's edge ranges:
//   covered pixels have e_i>=0, so inv*den <= S = sum max(e_ic+t_i,0)*rcp(z_i)
//   -> zp >= den/S = zlb. Cull when zlb > s_tzmax (margins swamp rcp error;
//   exact-path records have rcp=inf -> zlb=0/NaN -> kept; S=0 -> no coverage).
__global__ __launch_bounds__(256) void raster_kernel(
    const float4* __restrict__ rec, const uint2* __restrict__ sax,
    const unsigned short* __restrict__ stri, unsigned int* __restrict__ zbits,
    int F2, int F2c)
{
#pragma clang fp contract(off)
    __shared__ float4 sh[256];                 // 64 tris x 4 records
    __shared__ float2 s_kb[256];               // (sort key, bbox-pack-as-float)
    __shared__ unsigned short s_list[256];
    __shared__ int s_wk[4], s_kk[4], s_wo[4];
    __shared__ int s_tot, s_kc;
    __shared__ float s_tzmax, s_red[4];
    int zz = blockIdx.z;
    int b = zz / SPLIT, sp = zz - b*SPLIT;
    int tc = blockIdx.x, tr = blockIdx.y;
    int tid = threadIdx.x, lane = tid & 63, wv = tid >> 6;
    int tx = tid & 15, ty = tid >> 4;
    int col = tc*16 + tx, row = tr*16 + ty;
    float X = gval(col), Y = gval(row);
    int pc0 = tc*16, pc1 = pc0+15, pr0 = tr*16, pr1 = pr0+15;
    int wvs = __builtin_amdgcn_readfirstlane(wv);   // wave-uniform -> SGPR
    int wr0 = pr0 + wvs*4, wr1 = wr0 + 3;           // this wave's 4-row strip
    // tile rect over pixel CENTERS, for bin-time edge culling
    float Xc = 0.5f*(gval(pc0) + gval(pc1));
    float Yc = 0.5f*(gval(pr0) + gval(pr1));
    const float hxr = 15.0f/256.0f, hyr = 15.0f/256.0f;
    int seg = F2c / SPLIT;
    const float4* rb = rec + (size_t)b * F2 * 4;
    const uint2* sxb = sax + (size_t)b * F2c + (size_t)sp * seg;     // contiguous run
    const unsigned short* stb = stri + (size_t)b * F2c + (size_t)sp * seg;
    size_t pix = ((size_t)b*RASTN + row)*RASTN + col;
    unsigned int* zp_g = zbits + pix;
    float zmin = FARV;
    float pushed = FARV;     // min value known to already be in zbits[pix]
    if (tid == 0) s_tzmax = FARV;
    __syncthreads();
    int nch = (seg + 255) / 256;
    for (int c = 0; c < nch; ++c) {
        // coalesced scan of this split's sorted sub-stream (keys monotone)
        int s = c*256 + tid;
        bool kp = false, sv = false; unsigned int tri = 0; float kf = 0.0f;
        unsigned int pkv = 0;
        if (s < seg) {
            uint2 a = sxb[s];
            kf = __uint_as_float(a.y);
            kp = !(kf > s_tzmax);                  // conservative early-z (key <= minz)
            if (kp) {
                int pk = (int)a.x;
                int ic0 = pk & 255, ic1 = (pk >> 8) & 255;
                int ir0 = (pk >> 16) & 255, ir1 = (pk >> 24) & 255;
                sv = (ic0 <= ic1) && (ic0 <= pc1) && (ic1 >= pc0) && (ir0 <= pr1) && (ir1 >= pr0);
                if (sv) {
                    tri = stb[s];
                    pkv = a.x;
                    // ---- conservative 3-edge rect cull + hierarchical-z ----
                    float4 q0 = rb[(size_t)tri*4 + 0];
                    float4 q1 = rb[(size_t)tri*4 + 1];
                    float4 q2 = rb[(size_t)tri*4 + 2];   // (ra, rbz, rc, minz)
                    float a0 = q0.z, b0 = q0.w;
                    float a1 = q1.x, b1 = q1.y;
                    float xcd = Xc - q0.x, ycd = Yc - q0.y;
                    float e0c = (a0*xcd) + (b0*ycd);
                    float e1c = (a1*xcd) + (b1*ycd);
                    float den = q1.z;                  // folded: >= 0
                    float e2c = (den - e0c) - e1c;
                    float a2 = -(a0 + a1), b2 = -(b0 + b1);
                    float t0 = fabsf(a0)*hxr + fabsf(b0)*hyr;
                    float t1 = fabsf(a1)*hxr + fabsf(b1)*hyr;
                    float t2 = fabsf(a2)*hxr + fabsf(b2)*hyr;
                    float m0 = e0c + t0;
                    float m1 = e1c + t1;
                    float m2 = e2c + t2;
                    // relative margins swamp f32 eval error; cull only if provably
                    // every pixel center has a strictly negative barycentric
                    bool cull = (m0 < -1e-5f*(fabsf(e0c) + t0 + 1.0f))
                             || (m1 < -1e-5f*(fabsf(e1c) + t1 + 1.0f))
                             || (m2 < -1e-5f*(fabsf(e2c) + t2 + 1.0f));
                    if (cull) sv = false;
                    else {
                        // hier-z: zp over covered pixels >= den/S (conservative)
                        float e0m = fmaxf(m0, 0.0f);
                        float e1m = fmaxf(m1, 0.0f);
                        float e2m = fmaxf(m2, 0.0f);
                        float S = ((e0m*q2.x) + (e1m*q2.y)) + (e2m*q2.z);
                        S = S * (1.0f + 2e-3f);        // inflate: S >= true inv*den
                        float zlb = (den * __builtin_amdgcn_rcpf(S)) * (1.0f - 2e-3f);
                        if (zlb > s_tzmax) sv = false; // can't beat any pixel zmin
                        // (exact-path: rcp=inf -> S=inf/NaN -> zlb=0/NaN -> kept)
                    }
                }
            }
        }
        unsigned long long bs = __ballot(sv ? 1 : 0);
        unsigned long long bk = __ballot(kp ? 1 : 0);
        int pfx = __popcll(bs & ((1ull << lane) - 1ull));
        if (lane == 0) { s_wk[wv] = __popcll(bs); s_kk[wv] = __popcll(bk); }
        __syncthreads();
        if (tid == 0) {
            int acc = 0;
            for (int q = 0; q < 4; ++q) { s_wo[q] = acc; acc += s_wk[q]; }
            s_tot = acc;
            s_kc = s_kk[0] + s_kk[1] + s_kk[2] + s_kk[3];
        }
        __syncthreads();
        if (sv) {
            int pos = s_wo[wv] + pfx;
            s_list[pos] = (unsigned short)tri;
            s_kb[pos] = make_float2(kf, __uint_as_float(pkv));  // monotone keys
        }
        int kcnt = s_kc, n = s_tot;
        if (kcnt == 0) break;   // keys non-decreasing: all remaining > tzmax
        for (int g = 0; g < n; g += 64) {
            __syncthreads();
            // issue shared-z pull + per-lane (key,bbox) copy FIRST: the staging
            // barrier's implicit waits absorb their latency.
            float zg = __uint_as_float(__hip_atomic_load(
                zp_g, __ATOMIC_RELAXED, __HIP_MEMORY_SCOPE_AGENT));
            float2 kbv = s_kb[g + lane];   // lane l holds pair g+l (2-way, free)
            int cnt2 = (n - g) < 64 ? (n - g) : 64;
            if (tid < cnt2*4) {
                unsigned int t4 = s_list[g + (tid >> 2)];
                sh[tid] = rb[(size_t)t4*4 + (tid & 3)];
            }
            __syncthreads();
            pushed = fminf(pushed, zg);
            zmin = fminf(zmin, zg);
            int vkey = __float_as_int(kbv.x);
            int vbb  = __float_as_int(kbv.y);
            for (int i = 0; i < cnt2; ++i) {
                // register-file loop head: readlane (~4cy) replaces ds_read_b64
                float ky = __int_as_float(__builtin_amdgcn_readlane(vkey, i));
                if (ky > zmin) break;          // monotone: lane permanently done
                unsigned int pk = (unsigned int)__builtin_amdgcn_readlane(vbb, i);
                int ir0 = (int)((pk >> 16) & 255u), ir1 = (int)(pk >> 24);
                if (ir1 < wr0 || ir0 > wr1) continue;   // scalar row-strip reject
                int ic0 = (int)(pk & 255u), ic1 = (int)((pk >> 8) & 255u);
                if (col < ic0 || col > ic1 || row < ir0 || row > ir1) continue;
                float4 q0 = sh[i*4+0];
                float4 q1 = sh[i*4+1];
                float xc = X - q0.x;
                float yc = Y - q0.y;
                float e0 = (q0.z*xc) + (q0.w*yc);  // folded w0 numerator (= s0)
                float e1 = (q1.x*xc) + (q1.y*yc);  // folded w1 numerator
                float rd = q1.w;                   // rcp(dens), dens >= 0
                float w0a = e0*rd, w1a = e1*rd;    // approx w (filter only)
                float w2a = (1.0f - w0a) - w1a;
                float epsu = 1e-4f*((1.0f + fabsf(w0a)) + fabsf(w1a));
                if (e0 > -1e-30f && e1 > -1e-30f && w2a > -epsu) {
                    float4 q2 = sh[i*4+2];         // (ra, rbz, rc, minz)
                    float inva = ((w0a*q2.x) + (w1a*q2.y)) + (w2a*q2.z);
                    float zpa = __builtin_amdgcn_rcpf(inva);
                    bool clearly = (e0 > 0.0f) && (e1 > 0.0f) && (w2a > epsu) && (inva > 1e-6f);
                    // clearly-valid + approx-zp above zmin (w/ margin) provably
                    // cannot change the exact min -> skip the 6 IEEE divides
                    if (!clearly || zpa < zmin*1.001f) {
                        float4 q3 = sh[i*4+3];     // (pack, za, zb, zc)
                        float dens = q1.z;
                        float w0 = e0 / dens;      // (-e)/(-d) bit-exact == ref
                        float w1 = e1 / dens;
                        float w2 = (1.0f - w0) - w1;
                        float inv = ((w0 / q3.y) + (w1 / q3.z)) + (w2 / q3.w);
                        if ((w0 >= 0.0f) && (w1 >= 0.0f) && (w2 >= 0.0f) && (inv > 1e-8f)) {
                            float zp = 1.0f / inv; // exact div == ref zp
                            zmin = fminf(zmin, zp);
                        }
                    }
                }
            }
            // ---- push improvement so other splits can skip their warm-up
            if (zmin < pushed) {
                atomicMin(zp_g, __float_as_uint(zmin));   // bit-monotone positive floats
                pushed = zmin;
            }
        }
        if (n > 0) {
            // tile zmax refresh: only shrinks -> stays a conservative upper bound
            float zx = zmin;
            for (int o = 32; o; o >>= 1) zx = fmaxf(zx, __shfl_xor(zx, o));
            if (lane == 0) s_red[wv] = zx;
        }
        __syncthreads();
        if (n > 0 && tid == 0)
            s_tzmax = fminf(s_tzmax,
                fmaxf(fmaxf(s_red[0], s_red[1]), fmaxf(s_red[2], s_red[3])));
        __syncthreads();
    }
    if (zmin < pushed)
        atomicMin(zp_g, __float_as_uint(zmin));   // final publish
}

// ============ Kernel 3: per-batch minmax reduction + mask write (float4) =========
__global__ __launch_bounds__(256) void minmax_kernel(
    const float4* __restrict__ zbuf, float4* __restrict__ mask,
    unsigned int* __restrict__ mm, int npix)
{
    __shared__ float smx[4], smn[4];
    int b = blockIdx.y;
    size_t i4 = (((size_t)b * npix) >> 2) + (size_t)blockIdx.x * 256 + threadIdx.x;
    float4 z = zbuf[i4];
    float4 mk;
    mk.x = (z.x < FARV) ? 1.0f : 0.0f;
    mk.y = (z.y < FARV) ? 1.0f : 0.0f;
    mk.z = (z.z < FARV) ? 1.0f : 0.0f;
    mk.w = (z.w < FARV) ? 1.0f : 0.0f;
    mask[i4] = mk;                            // cover == any valid hit (z < FAR)
    float nbx = (z.x == FARV) ? 0.0f : z.x;   // (1-img_inf)*img
    float nby = (z.y == FARV) ? 0.0f : z.y;
    float nbz = (z.z == FARV) ? 0.0f : z.z;
    float nbw = (z.w == FARV) ? 0.0f : z.w;
    float vmx = fmaxf(fmaxf(nbx, nby), fmaxf(nbz, nbw));
    float vmn = fminf(fminf(z.x, z.y), fminf(z.z, z.w));
    int lane = threadIdx.x & 63, wv = threadIdx.x >> 6;
    for (int o = 32; o; o >>= 1) {
        vmx = fmaxf(vmx, __shfl_xor(vmx, o));
        vmn = fminf(vmn, __shfl_xor(vmn, o));
    }
    if (lane == 0) { smx[wv] = vmx; smn[wv] = vmn; }
    __syncthreads();
    if (threadIdx.x == 0) {
        float bmx = fmaxf(fmaxf(smx[0], smx[1]), fmaxf(smx[2], smx[3]));
        float bmn = fminf(fminf(smn[0], smn[1]), fminf(smn[2], smn[3]));
        atomicMax(mm + 2*b,     __float_as_uint(bmx));   // positive floats: bit-monotone
        atomicMin(mm + 2*b + 1, __float_as_uint(bmn));
    }
}

// ============ Kernel 4: normalize depth in place (float4) ========================
__global__ __launch_bounds__(256) void final_kernel(
    float4* __restrict__ zdep, const unsigned int* __restrict__ mm,
    int npix4, int total4)
{
#pragma clang fp contract(off)
    int idx = blockIdx.x*256 + threadIdx.x;
    if (idx >= total4) return;
    int b = idx / npix4;
    float mx = __uint_as_float(mm[2*b]);
    float mn = __uint_as_float(mm[2*b + 1]);
    float den = (mx - mn) + 1e-4f;
    float4 z = zdep[idx];
    float4 r;
    r.x = (mx - z.x) / den;
    r.y = (mx - z.y) / den;
    r.z = (mx - z.z) / den;
    r.w = (mx - z.w) / den;
    r.x = r.x < 0.0f ? 0.0f : (r.x > 1.0f ? 1.0f : r.x);
    r.y = r.y < 0.0f ? 0.0f : (r.y > 1.0f ? 1.0f : r.y);
    r.z = r.z < 0.0f ? 0.0f : (r.z > 1.0f ? 1.0f : r.z);
    r.w = r.w < 0.0f ? 0.0f : (r.w > 1.0f ? 1.0f : r.w);
    zdep[idx] = r;
}

extern "C" void kernel_launch(void* const* d_in, const int* in_sizes, int n_in,
                              void* d_out, int out_size, void* d_ws, size_t ws_size,
                              hipStream_t stream)
{
    const float* verts = (const float*)d_in[0];
    const int*   faces = (const int*)d_in[1];
    const float* Km    = (const float*)d_in[2];
    const float* Rm    = (const float*)d_in[3];
    const float* tm    = (const float*)d_in[4];
    const float* dm    = (const float*)d_in[5];
    float* out = (float*)d_out;

    int B  = in_sizes[2] / 9;          // intr is B*3*3
    int V  = in_sizes[0] / (3 * B);
    int F  = in_sizes[1] / (3 * B);
    int F2 = 2 * F;
    int F2c = ((F2 + SPLIT - 1) / SPLIT) * SPLIT;   // padded to SPLIT multiple
    int npix = RASTN * RASTN;

    char* ws = (char*)d_ws;
    size_t off = 0;
    float4* rec = (float4*)(ws + off);
    off = (off + (size_t)B * F2 * 4 * sizeof(float4) + 255) & ~(size_t)255;
    uint2* sax = (uint2*)(ws + off);
    off = (off + (size_t)B * F2c * sizeof(uint2) + 255) & ~(size_t)255;
    unsigned short* stri = (unsigned short*)(ws + off);
    off = (off + (size_t)B * F2c * sizeof(unsigned short) + 255) & ~(size_t)255;
    float* uvzg = (float*)(ws + off);
    off = (off + (size_t)B * V * 3 * sizeof(float) + 255) & ~(size_t)255;
    unsigned int* mm = (unsigned int*)(ws + off);

    unsigned int* zbits = (unsigned int*)out;    // depth region doubles as zbuf
    float* mask = out + (size_t)B * npix;

    dim3 pgrid(B, NINITY);
    prep_sort_kernel<<<pgrid, 1024, 0, stream>>>(
        verts, faces, Km, Rm, tm, dm, rec, sax, stri, zbits, mm, uvzg,
        V, F, F2, F2c, B, npix);
    dim3 rgrid(16, 16, B * SPLIT);
    raster_kernel<<<rgrid, 256, 0, stream>>>(rec, sax, stri, zbits, F2, F2c);
    dim3 mgrid(npix / 1024, B);
    minmax_kernel<<<mgrid, 256, 0, stream>>>(
        (const float4*)zbits, (float4*)mask, mm, npix);
    int npix4 = npix >> 2;
    int total4 = B * npix4;
    final_kernel<<<(total4 + 255) / 256, 256, 0, stream>>>(
        (float4*)zbits, mm, npix4, total4);
}